// Round 1
// baseline (878.123 us; speedup 1.0000x reference)
//
#include <hip/hip_runtime.h>

#define FIN 256
#define FE  64
#define FOUT 256

// ---------------- CSR build ----------------

__global__ void k_zero(int* __restrict__ p, int n) {
    int i = blockIdx.x * blockDim.x + threadIdx.x;
    if (i < n) p[i] = 0;
}

__global__ void k_deg(const int* __restrict__ src, const int* __restrict__ dst,
                      int* __restrict__ out_deg, int* __restrict__ in_deg, int E) {
    int i = blockIdx.x * blockDim.x + threadIdx.x;
    if (i < E) {
        atomicAdd(&out_deg[src[i]], 1);
        atomicAdd(&in_deg[dst[i]], 1);
    }
}

// single-block exclusive scan of in_deg -> row_ptr (and cursor copy)
__global__ void k_scan(const int* __restrict__ in_deg, int* __restrict__ row_ptr,
                       int* __restrict__ cursor, int N) {
    __shared__ int lds[1024];
    __shared__ int base_s;
    int t = threadIdx.x;
    if (t == 0) base_s = 0;
    __syncthreads();
    int nchunk = (N + 1023) / 1024;
    for (int c = 0; c < nchunk; c++) {
        int i = c * 1024 + t;
        int v = (i < N) ? in_deg[i] : 0;
        lds[t] = v;
        __syncthreads();
        for (int off = 1; off < 1024; off <<= 1) {
            int x = (t >= off) ? lds[t - off] : 0;
            __syncthreads();
            lds[t] += x;
            __syncthreads();
        }
        int excl = lds[t] - v;
        if (i < N) { row_ptr[i] = base_s + excl; cursor[i] = base_s + excl; }
        int tot = lds[1023];
        __syncthreads();
        if (t == 0) base_s += tot;
        __syncthreads();
    }
    if (t == 0) row_ptr[N] = base_s;
}

__global__ void k_norm(const int* __restrict__ out_deg, const int* __restrict__ in_deg,
                       float* __restrict__ norm_out, float* __restrict__ norm_in, int N) {
    int i = blockIdx.x * blockDim.x + threadIdx.x;
    if (i < N) {
        norm_out[i] = 1.0f / sqrtf((float)max(out_deg[i], 1));
        norm_in[i]  = 1.0f / sqrtf((float)max(in_deg[i], 1));
    }
}

__global__ void k_scatter(const int* __restrict__ src, const int* __restrict__ dst,
                          int* __restrict__ cursor, int* __restrict__ s_src,
                          int* __restrict__ s_eid, int E) {
    int i = blockIdx.x * blockDim.x + threadIdx.x;
    if (i < E) {
        int d = dst[i];
        int p = atomicAdd(&cursor[d], 1);
        s_src[p] = src[i];
        s_eid[p] = i;
    }
}

// ---------------- GEMM: out[M x 256] = (A ⊙ scale?) [M x K] @ W [K x 256] ----------------
// f32 vector FMA (no fp32 MFMA on CDNA4). 128x128 tile, 8x8 per thread, TK=16.

#define TM 128
#define TN 128
#define TK 16
#define LDSS 132  // padded row stride (keeps 16B alignment, breaks pow2 bank stride)

__global__ __launch_bounds__(256) void k_gemm(const float* __restrict__ A, int lda, int M, int K,
                                              const float* __restrict__ W,      // K x 256 row-major
                                              const float* __restrict__ scale,  // per-row of A, may be null
                                              float* __restrict__ out) {
    __shared__ float As[TK][LDSS];
    __shared__ float Bs[TK][LDSS];
    int m0 = blockIdx.y * TM;
    int n0 = blockIdx.x * TN;
    int t  = threadIdx.x;
    int wy = t >> 4;   // m-octet [0,16)
    int wx = t & 15;   // n-octet [0,16)

    float acc[8][8];
#pragma unroll
    for (int i = 0; i < 8; i++)
#pragma unroll
        for (int j = 0; j < 8; j++) acc[i][j] = 0.f;

    for (int k0 = 0; k0 < K; k0 += TK) {
        // A tile: 128 rows x 16 k  (512 float4 by 256 threads)
#pragma unroll
        for (int q = 0; q < 2; q++) {
            int idx = t + q * 256;     // 0..511
            int m   = idx >> 2;        // 0..127
            int kq  = idx & 3;         // 0..3
            int gm  = m0 + m;
            float4 a = make_float4(0.f, 0.f, 0.f, 0.f);
            if (gm < M) {
                a = *(const float4*)&A[(size_t)gm * lda + k0 + kq * 4];
                if (scale) { float s = scale[gm]; a.x *= s; a.y *= s; a.z *= s; a.w *= s; }
            }
            As[kq * 4 + 0][m] = a.x;
            As[kq * 4 + 1][m] = a.y;
            As[kq * 4 + 2][m] = a.z;
            As[kq * 4 + 3][m] = a.w;
        }
        // B tile: 16 rows x 128 cols (512 float4 by 256 threads)
#pragma unroll
        for (int q = 0; q < 2; q++) {
            int idx = t + q * 256;   // 0..511
            int r   = idx >> 5;      // 0..15
            int c4  = idx & 31;      // 0..31
            float4 b = *(const float4*)&W[(size_t)(k0 + r) * 256 + n0 + c4 * 4];
            *(float4*)&Bs[r][c4 * 4] = b;
        }
        __syncthreads();
#pragma unroll
        for (int kk = 0; kk < TK; kk++) {
            float4 a0 = *(const float4*)&As[kk][wy * 8];
            float4 a1 = *(const float4*)&As[kk][wy * 8 + 4];
            float4 b0 = *(const float4*)&Bs[kk][wx * 8];
            float4 b1 = *(const float4*)&Bs[kk][wx * 8 + 4];
            float av[8] = {a0.x, a0.y, a0.z, a0.w, a1.x, a1.y, a1.z, a1.w};
            float bv[8] = {b0.x, b0.y, b0.z, b0.w, b1.x, b1.y, b1.z, b1.w};
#pragma unroll
            for (int i = 0; i < 8; i++)
#pragma unroll
                for (int j = 0; j < 8; j++) acc[i][j] += av[i] * bv[j];
        }
        __syncthreads();
    }
#pragma unroll
    for (int i = 0; i < 8; i++) {
        int gm = m0 + wy * 8 + i;
        if (gm < M) {
            float4 o0 = make_float4(acc[i][0], acc[i][1], acc[i][2], acc[i][3]);
            float4 o1 = make_float4(acc[i][4], acc[i][5], acc[i][6], acc[i][7]);
            *(float4*)&out[(size_t)gm * 256 + n0 + wx * 8]     = o0;
            *(float4*)&out[(size_t)gm * 256 + n0 + wx * 8 + 4] = o1;
        }
    }
}

// ---------------- edge-feature aggregation: agg_e[n][c] = sum over in-edges ----------------
// one wave per node, lane = channel (FE=64)

__global__ __launch_bounds__(256) void k_agg_e(const float* __restrict__ edge_feat,
                                               const int* __restrict__ row_ptr,
                                               const int* __restrict__ s_eid,
                                               float* __restrict__ agg_e, int N) {
    int wave = threadIdx.x >> 6;
    int lane = threadIdx.x & 63;
    int n = blockIdx.x * 4 + wave;
    if (n >= N) return;
    int beg = row_ptr[n], end = row_ptr[n + 1];
    float acc = 0.f;
    for (int p = beg; p < end; p++) {
        int e = s_eid[p];
        acc += edge_feat[(size_t)e * FE + lane];
    }
    agg_e[(size_t)n * FE + lane] = acc;
}

// ---------------- final: out[n] = relu(norm_in[n] * (h2[n] + sum g[src]) + bias) ----------------
// h2 was staged into d_out by GEMM2. One wave per node, 4 floats/lane.

__global__ __launch_bounds__(256) void k_final(const float* __restrict__ g,
                                               const float* __restrict__ bias,
                                               const int* __restrict__ row_ptr,
                                               const int* __restrict__ s_src,
                                               const float* __restrict__ norm_in,
                                               float* __restrict__ out, int N) {
    int wave = threadIdx.x >> 6;
    int lane = threadIdx.x & 63;
    int n = blockIdx.x * 4 + wave;
    if (n >= N) return;
    int beg = row_ptr[n], end = row_ptr[n + 1];
    float4 acc = *(const float4*)&out[(size_t)n * FOUT + lane * 4];  // h2
    for (int p = beg; p < end; p++) {
        int s = s_src[p];
        float4 gg = *(const float4*)&g[(size_t)s * FOUT + lane * 4];
        acc.x += gg.x; acc.y += gg.y; acc.z += gg.z; acc.w += gg.w;
    }
    float ni = norm_in[n];
    float4 b4 = *(const float4*)&bias[lane * 4];
    float4 o;
    o.x = fmaxf(acc.x * ni + b4.x, 0.f);
    o.y = fmaxf(acc.y * ni + b4.y, 0.f);
    o.z = fmaxf(acc.z * ni + b4.z, 0.f);
    o.w = fmaxf(acc.w * ni + b4.w, 0.f);
    *(float4*)&out[(size_t)n * FOUT + lane * 4] = o;
}

// ---------------- launch ----------------

extern "C" void kernel_launch(void* const* d_in, const int* in_sizes, int n_in,
                              void* d_out, int out_size, void* d_ws, size_t ws_size,
                              hipStream_t stream) {
    const float* feat      = (const float*)d_in[0];
    const float* edge_feat = (const float*)d_in[1];
    const float* weight    = (const float*)d_in[2];  // [320 x 256] row-major
    const float* bias      = (const float*)d_in[3];
    const int*   src       = (const int*)d_in[4];
    const int*   dst       = (const int*)d_in[5];
    int E = in_sizes[4];
    int N = in_sizes[0] / FIN;

    char* ws = (char*)d_ws;
    size_t off = 0;
    auto alloc = [&](size_t bytes) -> void* {
        void* p = ws + off;
        off += (bytes + 255) & ~(size_t)255;
        return p;
    };
    float* g        = (float*)alloc((size_t)N * FOUT * 4);  // 51.2 MB
    float* agg_e    = (float*)alloc((size_t)N * FE * 4);    // 12.8 MB
    int*   out_deg  = (int*)alloc((size_t)N * 4);
    int*   in_deg   = (int*)alloc((size_t)N * 4);
    int*   row_ptr  = (int*)alloc((size_t)(N + 1) * 4);
    int*   cursor   = (int*)alloc((size_t)N * 4);
    float* norm_out = (float*)alloc((size_t)N * 4);
    float* norm_in  = (float*)alloc((size_t)N * 4);
    int*   s_src    = (int*)alloc((size_t)E * 4);
    int*   s_eid    = (int*)alloc((size_t)E * 4);
    (void)ws_size;

    int bN = (N + 255) / 256;
    int bE = (E + 255) / 256;

    k_zero<<<bN, 256, 0, stream>>>(out_deg, N);
    k_zero<<<bN, 256, 0, stream>>>(in_deg, N);
    k_deg<<<bE, 256, 0, stream>>>(src, dst, out_deg, in_deg, E);
    k_scan<<<1, 1024, 0, stream>>>(in_deg, row_ptr, cursor, N);
    k_norm<<<bN, 256, 0, stream>>>(out_deg, in_deg, norm_out, norm_in, N);
    k_scatter<<<bE, 256, 0, stream>>>(src, dst, cursor, s_src, s_eid, E);

    // GEMM1: g = (feat ⊙ norm_out) @ W_h   [N,256]@[256,256]
    dim3 gg1(FOUT / TN, (N + TM - 1) / TM);
    k_gemm<<<gg1, 256, 0, stream>>>(feat, FIN, N, FIN, weight, norm_out, g);

    // edge aggregation: agg_e [N,64]
    k_agg_e<<<(N + 3) / 4, 256, 0, stream>>>(edge_feat, row_ptr, s_eid, agg_e, N);

    // GEMM2: h2 = agg_e @ W_e  [N,64]@[64,256], staged into d_out
    k_gemm<<<gg1, 256, 0, stream>>>(agg_e, FE, N, FE, weight + (size_t)FIN * FOUT,
                                    nullptr, (float*)d_out);

    // final: gather g rows per dst, add h2, normalize, bias, relu
    k_final<<<(N + 3) / 4, 256, 0, stream>>>(g, bias, row_ptr, s_src, norm_in,
                                             (float*)d_out, N);
}

// Round 2
// 855.955 us; speedup vs baseline: 1.0259x; 1.0259x over previous
//
#include <hip/hip_runtime.h>

#define FIN 256
#define FE  64
#define FOUT 256

// ---------------- CSR build ----------------

__global__ void k_deg(const int* __restrict__ src, const int* __restrict__ dst,
                      int* __restrict__ out_deg, int* __restrict__ in_deg, int E) {
    int i = blockIdx.x * blockDim.x + threadIdx.x;
    if (i < E) {
        atomicAdd(&out_deg[src[i]], 1);
        atomicAdd(&in_deg[dst[i]], 1);
    }
}

// single-block exclusive scan of in_deg -> row_ptr (and cursor copy)
// wave-shuffle based: 3 barriers per 1024-chunk instead of 20.
__global__ void k_scan(const int* __restrict__ in_deg, int* __restrict__ row_ptr,
                       int* __restrict__ cursor, int N) {
    __shared__ int wsum[16];
    __shared__ int woff[17];
    __shared__ int base_s;
    int t = threadIdx.x, lane = t & 63, w = t >> 6;
    if (t == 0) base_s = 0;
    __syncthreads();
    int nchunk = (N + 1023) >> 10;
    for (int c = 0; c < nchunk; c++) {
        int i = (c << 10) + t;
        int v = (i < N) ? in_deg[i] : 0;
        int incl = v;
#pragma unroll
        for (int off = 1; off < 64; off <<= 1) {
            int x = __shfl_up(incl, off, 64);
            if (lane >= off) incl += x;
        }
        if (lane == 63) wsum[w] = incl;
        __syncthreads();
        if (w == 0 && lane < 16) {
            int s = wsum[lane];
            int sc = s;
#pragma unroll
            for (int off = 1; off < 16; off <<= 1) {
                int x = __shfl_up(sc, off, 64);
                if (lane >= off) sc += x;
            }
            woff[lane] = sc - s;            // exclusive wave offset
            if (lane == 15) woff[16] = sc;  // chunk total
        }
        __syncthreads();
        int excl = base_s + woff[w] + incl - v;
        if (i < N) { row_ptr[i] = excl; cursor[i] = excl; }
        int tot = woff[16];
        __syncthreads();
        if (t == 0) base_s += tot;
        __syncthreads();
    }
    if (t == 0) row_ptr[N] = base_s;
}

__global__ void k_norm(const int* __restrict__ out_deg, const int* __restrict__ in_deg,
                       float* __restrict__ norm_out, float* __restrict__ norm_in, int N) {
    int i = blockIdx.x * blockDim.x + threadIdx.x;
    if (i < N) {
        norm_out[i] = 1.0f / sqrtf((float)max(out_deg[i], 1));
        norm_in[i]  = 1.0f / sqrtf((float)max(in_deg[i], 1));
    }
}

__global__ void k_scatter(const int* __restrict__ src, const int* __restrict__ dst,
                          int* __restrict__ cursor, int* __restrict__ s_src, int E) {
    int i = blockIdx.x * blockDim.x + threadIdx.x;
    if (i < E) {
        int d = dst[i];
        int p = atomicAdd(&cursor[d], 1);
        s_src[p] = src[i];
    }
}

// ---------------- GEMM: out[M x 256] = (A ⊙ scale?) [M x K] @ W [K x 256] ----------------
// f32 vector FMA (no fp32 MFMA on CDNA4). 128x128 tile, 8x8 per thread, TK=16.

#define TM 128
#define TN 128
#define TK 16
#define LDSS 132  // padded row stride

__global__ __launch_bounds__(256) void k_gemm(const float* __restrict__ A, int lda, int M, int K,
                                              const float* __restrict__ W,      // K x 256 row-major
                                              const float* __restrict__ scale,  // per-row of A, may be null
                                              float* __restrict__ out) {
    __shared__ float As[TK][LDSS];
    __shared__ float Bs[TK][LDSS];
    int m0 = blockIdx.y * TM;
    int n0 = blockIdx.x * TN;
    int t  = threadIdx.x;
    int wy = t >> 4;   // m-octet [0,16)
    int wx = t & 15;   // n-octet [0,16)

    float acc[8][8];
#pragma unroll
    for (int i = 0; i < 8; i++)
#pragma unroll
        for (int j = 0; j < 8; j++) acc[i][j] = 0.f;

    for (int k0 = 0; k0 < K; k0 += TK) {
#pragma unroll
        for (int q = 0; q < 2; q++) {
            int idx = t + q * 256;     // 0..511
            int m   = idx >> 2;        // 0..127
            int kq  = idx & 3;         // 0..3
            int gm  = m0 + m;
            float4 a = make_float4(0.f, 0.f, 0.f, 0.f);
            if (gm < M) {
                a = *(const float4*)&A[(size_t)gm * lda + k0 + kq * 4];
                if (scale) { float s = scale[gm]; a.x *= s; a.y *= s; a.z *= s; a.w *= s; }
            }
            As[kq * 4 + 0][m] = a.x;
            As[kq * 4 + 1][m] = a.y;
            As[kq * 4 + 2][m] = a.z;
            As[kq * 4 + 3][m] = a.w;
        }
#pragma unroll
        for (int q = 0; q < 2; q++) {
            int idx = t + q * 256;   // 0..511
            int r   = idx >> 5;      // 0..15
            int c4  = idx & 31;      // 0..31
            float4 b = *(const float4*)&W[(size_t)(k0 + r) * 256 + n0 + c4 * 4];
            *(float4*)&Bs[r][c4 * 4] = b;
        }
        __syncthreads();
#pragma unroll
        for (int kk = 0; kk < TK; kk++) {
            float4 a0 = *(const float4*)&As[kk][wy * 8];
            float4 a1 = *(const float4*)&As[kk][wy * 8 + 4];
            float4 b0 = *(const float4*)&Bs[kk][wx * 8];
            float4 b1 = *(const float4*)&Bs[kk][wx * 8 + 4];
            float av[8] = {a0.x, a0.y, a0.z, a0.w, a1.x, a1.y, a1.z, a1.w};
            float bv[8] = {b0.x, b0.y, b0.z, b0.w, b1.x, b1.y, b1.z, b1.w};
#pragma unroll
            for (int i = 0; i < 8; i++)
#pragma unroll
                for (int j = 0; j < 8; j++) acc[i][j] += av[i] * bv[j];
        }
        __syncthreads();
    }
#pragma unroll
    for (int i = 0; i < 8; i++) {
        int gm = m0 + wy * 8 + i;
        if (gm < M) {
            float4 o0 = make_float4(acc[i][0], acc[i][1], acc[i][2], acc[i][3]);
            float4 o1 = make_float4(acc[i][4], acc[i][5], acc[i][6], acc[i][7]);
            *(float4*)&out[(size_t)gm * 256 + n0 + wx * 8]     = o0;
            *(float4*)&out[(size_t)gm * 256 + n0 + wx * 8 + 4] = o1;
        }
    }
}

// ---------------- edge aggregation, v2: edge-parallel atomic streaming ----------------
// one wave per edge; lane = channel. edge_feat read in ORIGINAL order (coalesced
// 256B/wave); scatter-add into 12.8MB agg_e (L2/L3-resident, low contention).

__global__ __launch_bounds__(256) void k_agg_e_atomic(const float* __restrict__ edge_feat,
                                                      const int* __restrict__ dst,
                                                      float* __restrict__ agg_e, int E) {
    int gid = blockIdx.x * 256 + threadIdx.x;
    int e = gid >> 6;
    if (e >= E) return;
    int lane = gid & 63;
    int d = dst[e];
    float v = edge_feat[(size_t)e * FE + lane];
    atomicAdd(&agg_e[(size_t)d * FE + lane], v);
}

// ---------------- final, v2: out[n] = relu(norm_in[n]*(h2[n] + sum g[src]) + bias) ----
// h2 staged in d_out. One wave per (node, 64-channel slice) -> 4 waves/node,
// unroll-4 with index prefetch for 4 independent gather loads in flight.

__global__ __launch_bounds__(256) void k_final(const float* __restrict__ g,
                                               const float* __restrict__ bias,
                                               const int* __restrict__ row_ptr,
                                               const int* __restrict__ s_src,
                                               const float* __restrict__ norm_in,
                                               float* __restrict__ out, int N) {
    int w = threadIdx.x >> 6;
    int lane = threadIdx.x & 63;
    int n = blockIdx.x;
    if (n >= N) return;
    int c = w * 64 + lane;  // channel [0,256)
    int beg = row_ptr[n], end = row_ptr[n + 1];
    float acc = out[(size_t)n * FOUT + c];  // h2
    int p = beg;
    for (; p + 3 < end; p += 4) {
        int s0 = s_src[p];
        int s1 = s_src[p + 1];
        int s2 = s_src[p + 2];
        int s3 = s_src[p + 3];
        float g0 = g[(size_t)s0 * FOUT + c];
        float g1 = g[(size_t)s1 * FOUT + c];
        float g2 = g[(size_t)s2 * FOUT + c];
        float g3 = g[(size_t)s3 * FOUT + c];
        acc += (g0 + g1) + (g2 + g3);
    }
    for (; p < end; p++) acc += g[(size_t)s_src[p] * FOUT + c];
    float ni = norm_in[n];
    float o = fmaxf(acc * ni + bias[c], 0.f);
    out[(size_t)n * FOUT + c] = o;
}

// ---------------- launch ----------------

extern "C" void kernel_launch(void* const* d_in, const int* in_sizes, int n_in,
                              void* d_out, int out_size, void* d_ws, size_t ws_size,
                              hipStream_t stream) {
    const float* feat      = (const float*)d_in[0];
    const float* edge_feat = (const float*)d_in[1];
    const float* weight    = (const float*)d_in[2];  // [320 x 256] row-major
    const float* bias      = (const float*)d_in[3];
    const int*   src       = (const int*)d_in[4];
    const int*   dst       = (const int*)d_in[5];
    int E = in_sizes[4];
    int N = in_sizes[0] / FIN;

    char* ws = (char*)d_ws;
    size_t off = 0;
    auto alloc = [&](size_t bytes) -> void* {
        void* p = ws + off;
        off += (bytes + 255) & ~(size_t)255;
        return p;
    };
    float* g        = (float*)alloc((size_t)N * FOUT * 4);  // 51.2 MB
    float* agg_e    = (float*)alloc((size_t)N * FE * 4);    // 12.8 MB
    int*   out_deg  = (int*)alloc((size_t)N * 4);
    int*   in_deg   = (int*)alloc((size_t)N * 4);
    int*   row_ptr  = (int*)alloc((size_t)(N + 1) * 4);
    int*   cursor   = (int*)alloc((size_t)N * 4);
    float* norm_out = (float*)alloc((size_t)N * 4);
    float* norm_in  = (float*)alloc((size_t)N * 4);
    int*   s_src    = (int*)alloc((size_t)E * 4);
    (void)ws_size;

    int bE = (E + 255) / 256;

    hipMemsetAsync(out_deg, 0, (size_t)N * 4, stream);
    hipMemsetAsync(in_deg, 0, (size_t)N * 4, stream);
    hipMemsetAsync(agg_e, 0, (size_t)N * FE * 4, stream);

    k_deg<<<bE, 256, 0, stream>>>(src, dst, out_deg, in_deg, E);
    k_scan<<<1, 1024, 0, stream>>>(in_deg, row_ptr, cursor, N);
    k_norm<<<(N + 255) / 256, 256, 0, stream>>>(out_deg, in_deg, norm_out, norm_in, N);
    k_scatter<<<bE, 256, 0, stream>>>(src, dst, cursor, s_src, E);

    // GEMM1: g = (feat ⊙ norm_out) @ W_h   [N,256]@[256,256]
    dim3 gg1(FOUT / TN, (N + TM - 1) / TM);
    k_gemm<<<gg1, 256, 0, stream>>>(feat, FIN, N, FIN, weight, norm_out, g);

    // edge aggregation: agg_e [N,64] via coalesced atomic streaming
    k_agg_e_atomic<<<(E * 64 + 255) / 256, 256, 0, stream>>>(edge_feat, dst, agg_e, E);

    // GEMM2: h2 = agg_e @ W_e  [N,64]@[64,256], staged into d_out
    k_gemm<<<gg1, 256, 0, stream>>>(agg_e, FE, N, FE, weight + (size_t)FIN * FOUT,
                                    nullptr, (float*)d_out);

    // final: gather g rows per dst (4 waves/node), add h2, normalize, bias, relu
    k_final<<<N, 256, 0, stream>>>(g, bias, row_ptr, s_src, norm_in, (float*)d_out, N);
}

// Round 3
// 729.111 us; speedup vs baseline: 1.2044x; 1.1740x over previous
//
#include <hip/hip_runtime.h>

#define FIN 256
#define FE  64
#define FOUT 256

// ---------------- CSR build ----------------

__global__ void k_deg(const int* __restrict__ src, const int* __restrict__ dst,
                      int* __restrict__ out_deg, int* __restrict__ in_deg, int E) {
    int i = blockIdx.x * blockDim.x + threadIdx.x;
    if (i < E) {
        atomicAdd(&out_deg[src[i]], 1);
        atomicAdd(&in_deg[dst[i]], 1);
    }
}

// scan-free multi-block exclusive scan: block b redundantly sums in_deg[0..b*1024)
// (<=200KB, L2-resident) then shuffle-scans its own 1024-chunk. No inter-block dep.
__global__ __launch_bounds__(1024) void k_scan(const int* __restrict__ in_deg,
                                               int* __restrict__ row_ptr,
                                               int* __restrict__ cursor, int N) {
    __shared__ int red[16];
    __shared__ int wsum[16];
    __shared__ int wo[17];
    int b = blockIdx.x, t = threadIdx.x;
    int lane = t & 63, w = t >> 6;
    int limit = b << 10;

    // phase 1: base = sum of in_deg[0 .. limit)
    int part = 0;
    for (int i = t; i < limit; i += 1024) part += in_deg[i];
#pragma unroll
    for (int off = 32; off; off >>= 1) part += __shfl_down(part, off, 64);
    if (lane == 0) red[w] = part;
    __syncthreads();
    if (t == 0) {
        int s = 0;
#pragma unroll
        for (int k = 0; k < 16; k++) s += red[k];
        red[0] = s;
    }
    __syncthreads();
    int base = red[0];

    // phase 2: shuffle-scan own chunk
    int i = limit + t;
    int v = (i < N) ? in_deg[i] : 0;
    int incl = v;
#pragma unroll
    for (int off = 1; off < 64; off <<= 1) {
        int x = __shfl_up(incl, off, 64);
        if (lane >= off) incl += x;
    }
    if (lane == 63) wsum[w] = incl;
    __syncthreads();
    if (w == 0 && lane < 16) {
        int s = wsum[lane];
        int sc = s;
#pragma unroll
        for (int off = 1; off < 16; off <<= 1) {
            int x = __shfl_up(sc, off, 64);
            if (lane >= off) sc += x;
        }
        wo[lane] = sc - s;
        if (lane == 15) wo[16] = sc;
    }
    __syncthreads();
    int excl = base + wo[w] + incl - v;
    if (i < N) { row_ptr[i] = excl; cursor[i] = excl; }
    if (t == 0 && i + 1024 > N && i < N + 1024) row_ptr[N] = base + wo[16];
}

__global__ void k_norm(const int* __restrict__ out_deg, const int* __restrict__ in_deg,
                       float* __restrict__ norm_out, float* __restrict__ norm_in, int N) {
    int i = blockIdx.x * blockDim.x + threadIdx.x;
    if (i < N) {
        norm_out[i] = 1.0f / sqrtf((float)max(out_deg[i], 1));
        norm_in[i]  = 1.0f / sqrtf((float)max(in_deg[i], 1));
    }
}

__global__ void k_scatter(const int* __restrict__ src, const int* __restrict__ dst,
                          int* __restrict__ cursor, int* __restrict__ s_src,
                          int* __restrict__ s_eid, int E) {
    int i = blockIdx.x * blockDim.x + threadIdx.x;
    if (i < E) {
        int d = dst[i];
        int p = atomicAdd(&cursor[d], 1);
        s_src[p] = src[i];
        s_eid[p] = i;
    }
}

// ---------------- GEMM: out[M x 256] = (A ⊙ scale?) [M x K] @ W [K x 256] ----------------

#define TM 128
#define TN 128
#define TK 16
#define LDSS 132

__global__ __launch_bounds__(256) void k_gemm(const float* __restrict__ A, int lda, int M, int K,
                                              const float* __restrict__ W,
                                              const float* __restrict__ scale,
                                              float* __restrict__ out) {
    __shared__ float As[TK][LDSS];
    __shared__ float Bs[TK][LDSS];
    int m0 = blockIdx.y * TM;
    int n0 = blockIdx.x * TN;
    int t  = threadIdx.x;
    int wy = t >> 4;
    int wx = t & 15;

    float acc[8][8];
#pragma unroll
    for (int i = 0; i < 8; i++)
#pragma unroll
        for (int j = 0; j < 8; j++) acc[i][j] = 0.f;

    for (int k0 = 0; k0 < K; k0 += TK) {
#pragma unroll
        for (int q = 0; q < 2; q++) {
            int idx = t + q * 256;
            int m   = idx >> 2;
            int kq  = idx & 3;
            int gm  = m0 + m;
            float4 a = make_float4(0.f, 0.f, 0.f, 0.f);
            if (gm < M) {
                a = *(const float4*)&A[(size_t)gm * lda + k0 + kq * 4];
                if (scale) { float s = scale[gm]; a.x *= s; a.y *= s; a.z *= s; a.w *= s; }
            }
            As[kq * 4 + 0][m] = a.x;
            As[kq * 4 + 1][m] = a.y;
            As[kq * 4 + 2][m] = a.z;
            As[kq * 4 + 3][m] = a.w;
        }
#pragma unroll
        for (int q = 0; q < 2; q++) {
            int idx = t + q * 256;
            int r   = idx >> 5;
            int c4  = idx & 31;
            float4 bv = *(const float4*)&W[(size_t)(k0 + r) * 256 + n0 + c4 * 4];
            *(float4*)&Bs[r][c4 * 4] = bv;
        }
        __syncthreads();
#pragma unroll
        for (int kk = 0; kk < TK; kk++) {
            float4 a0 = *(const float4*)&As[kk][wy * 8];
            float4 a1 = *(const float4*)&As[kk][wy * 8 + 4];
            float4 b0 = *(const float4*)&Bs[kk][wx * 8];
            float4 b1 = *(const float4*)&Bs[kk][wx * 8 + 4];
            float av[8] = {a0.x, a0.y, a0.z, a0.w, a1.x, a1.y, a1.z, a1.w};
            float bv[8] = {b0.x, b0.y, b0.z, b0.w, b1.x, b1.y, b1.z, b1.w};
#pragma unroll
            for (int i = 0; i < 8; i++)
#pragma unroll
                for (int j = 0; j < 8; j++) acc[i][j] += av[i] * bv[j];
        }
        __syncthreads();
    }
#pragma unroll
    for (int i = 0; i < 8; i++) {
        int gm = m0 + wy * 8 + i;
        if (gm < M) {
            float4 o0 = make_float4(acc[i][0], acc[i][1], acc[i][2], acc[i][3]);
            float4 o1 = make_float4(acc[i][4], acc[i][5], acc[i][6], acc[i][7]);
            *(float4*)&out[(size_t)gm * 256 + n0 + wx * 8]     = o0;
            *(float4*)&out[(size_t)gm * 256 + n0 + wx * 8 + 4] = o1;
        }
    }
}

// ---------------- edge aggregation v3: CSR gather, unroll-8 prefetch ----------------
// one wave per node, lane = channel; 8 independent coalesced 256B row loads in flight.

__global__ __launch_bounds__(256) void k_agg_e(const float* __restrict__ edge_feat,
                                               const int* __restrict__ row_ptr,
                                               const int* __restrict__ s_eid,
                                               float* __restrict__ agg_e, int N) {
    int w = threadIdx.x >> 6;
    int lane = threadIdx.x & 63;
    int n = blockIdx.x * 4 + w;
    if (n >= N) return;
    int beg = row_ptr[n], end = row_ptr[n + 1];
    float acc = 0.f;
    int p = beg;
    for (; p + 8 <= end; p += 8) {
        int e0 = s_eid[p + 0], e1 = s_eid[p + 1], e2 = s_eid[p + 2], e3 = s_eid[p + 3];
        int e4 = s_eid[p + 4], e5 = s_eid[p + 5], e6 = s_eid[p + 6], e7 = s_eid[p + 7];
        float v0 = edge_feat[(size_t)e0 * FE + lane];
        float v1 = edge_feat[(size_t)e1 * FE + lane];
        float v2 = edge_feat[(size_t)e2 * FE + lane];
        float v3 = edge_feat[(size_t)e3 * FE + lane];
        float v4 = edge_feat[(size_t)e4 * FE + lane];
        float v5 = edge_feat[(size_t)e5 * FE + lane];
        float v6 = edge_feat[(size_t)e6 * FE + lane];
        float v7 = edge_feat[(size_t)e7 * FE + lane];
        acc += ((v0 + v1) + (v2 + v3)) + ((v4 + v5) + (v6 + v7));
    }
    for (; p < end; p++) acc += edge_feat[(size_t)s_eid[p] * FE + lane];
    agg_e[(size_t)n * FE + lane] = acc;
}

// ---------------- final: out[n] = relu(norm_in[n]*(h2[n] + sum g[src]) + bias) ----
// h2 staged in d_out. 4 waves/node (one per 64-ch slice), unroll-8 prefetch.

__global__ __launch_bounds__(256) void k_final(const float* __restrict__ g,
                                               const float* __restrict__ bias,
                                               const int* __restrict__ row_ptr,
                                               const int* __restrict__ s_src,
                                               const float* __restrict__ norm_in,
                                               float* __restrict__ out, int N) {
    int w = threadIdx.x >> 6;
    int lane = threadIdx.x & 63;
    int n = blockIdx.x;
    if (n >= N) return;
    int c = w * 64 + lane;
    int beg = row_ptr[n], end = row_ptr[n + 1];
    float acc = out[(size_t)n * FOUT + c];
    int p = beg;
    for (; p + 8 <= end; p += 8) {
        int s0 = s_src[p + 0], s1 = s_src[p + 1], s2 = s_src[p + 2], s3 = s_src[p + 3];
        int s4 = s_src[p + 4], s5 = s_src[p + 5], s6 = s_src[p + 6], s7 = s_src[p + 7];
        float g0 = g[(size_t)s0 * FOUT + c];
        float g1 = g[(size_t)s1 * FOUT + c];
        float g2 = g[(size_t)s2 * FOUT + c];
        float g3 = g[(size_t)s3 * FOUT + c];
        float g4 = g[(size_t)s4 * FOUT + c];
        float g5 = g[(size_t)s5 * FOUT + c];
        float g6 = g[(size_t)s6 * FOUT + c];
        float g7 = g[(size_t)s7 * FOUT + c];
        acc += ((g0 + g1) + (g2 + g3)) + ((g4 + g5) + (g6 + g7));
    }
    for (; p < end; p++) acc += g[(size_t)s_src[p] * FOUT + c];
    float ni = norm_in[n];
    float o = fmaxf(acc * ni + bias[c], 0.f);
    out[(size_t)n * FOUT + c] = o;
}

// ---------------- launch ----------------

extern "C" void kernel_launch(void* const* d_in, const int* in_sizes, int n_in,
                              void* d_out, int out_size, void* d_ws, size_t ws_size,
                              hipStream_t stream) {
    const float* feat      = (const float*)d_in[0];
    const float* edge_feat = (const float*)d_in[1];
    const float* weight    = (const float*)d_in[2];
    const float* bias      = (const float*)d_in[3];
    const int*   src       = (const int*)d_in[4];
    const int*   dst       = (const int*)d_in[5];
    int E = in_sizes[4];
    int N = in_sizes[0] / FIN;

    char* ws = (char*)d_ws;
    size_t off = 0;
    auto alloc = [&](size_t bytes) -> void* {
        void* p = ws + off;
        off += (bytes + 255) & ~(size_t)255;
        return p;
    };
    float* g        = (float*)alloc((size_t)N * FOUT * 4);
    float* agg_e    = (float*)alloc((size_t)N * FE * 4);
    int*   out_deg  = (int*)alloc((size_t)N * 4);
    int*   in_deg   = (int*)alloc((size_t)N * 4);
    int*   row_ptr  = (int*)alloc((size_t)(N + 1) * 4);
    int*   cursor   = (int*)alloc((size_t)N * 4);
    float* norm_out = (float*)alloc((size_t)N * 4);
    float* norm_in  = (float*)alloc((size_t)N * 4);
    int*   s_src    = (int*)alloc((size_t)E * 4);
    int*   s_eid    = (int*)alloc((size_t)E * 4);
    (void)ws_size;

    int bE = (E + 255) / 256;
    int nchunk = (N + 1023) >> 10;

    hipMemsetAsync(out_deg, 0, (size_t)N * 4, stream);
    hipMemsetAsync(in_deg, 0, (size_t)N * 4, stream);

    k_deg<<<bE, 256, 0, stream>>>(src, dst, out_deg, in_deg, E);
    k_scan<<<nchunk, 1024, 0, stream>>>(in_deg, row_ptr, cursor, N);
    k_norm<<<(N + 255) / 256, 256, 0, stream>>>(out_deg, in_deg, norm_out, norm_in, N);
    k_scatter<<<bE, 256, 0, stream>>>(src, dst, cursor, s_src, s_eid, E);

    // GEMM1: g = (feat ⊙ norm_out) @ W_h   [N,256]@[256,256]
    dim3 gg1(FOUT / TN, (N + TM - 1) / TM);
    k_gemm<<<gg1, 256, 0, stream>>>(feat, FIN, N, FIN, weight, norm_out, g);

    // edge aggregation: agg_e [N,64] via CSR gather
    k_agg_e<<<(N + 3) / 4, 256, 0, stream>>>(edge_feat, row_ptr, s_eid, agg_e, N);

    // GEMM2: h2 = agg_e @ W_e  [N,64]@[64,256], staged into d_out
    k_gemm<<<gg1, 256, 0, stream>>>(agg_e, FE, N, FE, weight + (size_t)FIN * FOUT,
                                    nullptr, (float*)d_out);

    // final: gather g rows per dst (4 waves/node), add h2, normalize, bias, relu
    k_final<<<N, 256, 0, stream>>>(g, bias, row_ptr, s_src, norm_in, (float*)d_out, N);
}

// Round 4
// 600.493 us; speedup vs baseline: 1.4623x; 1.2142x over previous
//
#include <hip/hip_runtime.h>

#define FIN 256
#define FE  64
#define FOUT 256

typedef __attribute__((ext_vector_type(8))) short short8;
typedef __attribute__((ext_vector_type(4))) float f32x4;

__device__ inline unsigned short f2bf(float f) {  // RNE
    unsigned int u = __builtin_bit_cast(unsigned int, f);
    u += 0x7fffu + ((u >> 16) & 1u);
    return (unsigned short)(u >> 16);
}
__device__ inline float bf2f(unsigned short b) {
    unsigned int u = ((unsigned int)b) << 16;
    return __builtin_bit_cast(float, u);
}

// ---------------- CSR build ----------------

__global__ void k_deg(const int* __restrict__ src, const int* __restrict__ dst,
                      int* __restrict__ out_deg, int* __restrict__ in_deg, int E) {
    int i = blockIdx.x * blockDim.x + threadIdx.x;
    if (i < E) {
        atomicAdd(&out_deg[src[i]], 1);
        atomicAdd(&in_deg[dst[i]], 1);
    }
}

// scan-free multi-block exclusive scan: block b redundantly sums in_deg[0..b*1024)
__global__ __launch_bounds__(1024) void k_scan(const int* __restrict__ in_deg,
                                               int* __restrict__ row_ptr,
                                               int* __restrict__ cursor, int N) {
    __shared__ int red[16];
    __shared__ int wsum[16];
    __shared__ int wo[17];
    int b = blockIdx.x, t = threadIdx.x;
    int lane = t & 63, w = t >> 6;
    int limit = b << 10;

    int part = 0;
    for (int i = t; i < limit; i += 1024) part += in_deg[i];
#pragma unroll
    for (int off = 32; off; off >>= 1) part += __shfl_down(part, off, 64);
    if (lane == 0) red[w] = part;
    __syncthreads();
    if (t == 0) {
        int s = 0;
#pragma unroll
        for (int k = 0; k < 16; k++) s += red[k];
        red[0] = s;
    }
    __syncthreads();
    int base = red[0];

    int i = limit + t;
    int v = (i < N) ? in_deg[i] : 0;
    int incl = v;
#pragma unroll
    for (int off = 1; off < 64; off <<= 1) {
        int x = __shfl_up(incl, off, 64);
        if (lane >= off) incl += x;
    }
    if (lane == 63) wsum[w] = incl;
    __syncthreads();
    if (w == 0 && lane < 16) {
        int s = wsum[lane];
        int sc = s;
#pragma unroll
        for (int off = 1; off < 16; off <<= 1) {
            int x = __shfl_up(sc, off, 64);
            if (lane >= off) sc += x;
        }
        wo[lane] = sc - s;
        if (lane == 15) wo[16] = sc;
    }
    __syncthreads();
    int excl = base + wo[w] + incl - v;
    if (i < N) { row_ptr[i] = excl; cursor[i] = excl; }
    if (t == 0 && i + 1024 > N && i < N + 1024) row_ptr[N] = base + wo[16];
}

__global__ void k_norm(const int* __restrict__ out_deg, const int* __restrict__ in_deg,
                       float* __restrict__ norm_out, float* __restrict__ norm_in, int N) {
    int i = blockIdx.x * blockDim.x + threadIdx.x;
    if (i < N) {
        norm_out[i] = 1.0f / sqrtf((float)max(out_deg[i], 1));
        norm_in[i]  = 1.0f / sqrtf((float)max(in_deg[i], 1));
    }
}

__global__ void k_scatter(const int* __restrict__ src, const int* __restrict__ dst,
                          int* __restrict__ cursor, int* __restrict__ s_src,
                          int* __restrict__ s_eid, int E) {
    int i = blockIdx.x * blockDim.x + threadIdx.x;
    if (i < E) {
        int d = dst[i];
        int p = atomicAdd(&cursor[d], 1);
        s_src[p] = src[i];
        s_eid[p] = i;
    }
}

// ---------------- bf16 prep passes ----------------

// featb[m][k] = bf16(feat[m][k] * norm_out[m]); 4 elems/thread
__global__ void k_prep_feat(const float* __restrict__ feat, const float* __restrict__ norm_out,
                            unsigned short* __restrict__ featb, int N) {
    int i = blockIdx.x * 256 + threadIdx.x;
    if (i >= N * 64) return;
    int m = i >> 6, c4 = (i & 63) * 4;
    float s = norm_out[m];
    float4 v = *(const float4*)&feat[(size_t)m * FIN + c4];
    ushort4 o;
    o.x = f2bf(v.x * s); o.y = f2bf(v.y * s); o.z = f2bf(v.z * s); o.w = f2bf(v.w * s);
    *(ushort4*)&featb[(size_t)m * FIN + c4] = o;
}

// transpose weight [320 x 256] f32 -> wt_h [256 n][256 k] bf16, wt_e [256 n][64 k] bf16
__global__ void k_prep_w(const float* __restrict__ w, unsigned short* __restrict__ wt_h,
                         unsigned short* __restrict__ wt_e) {
    int i = blockIdx.x * 256 + threadIdx.x;
    if (i >= 320 * 256) return;
    int k = i >> 8, n = i & 255;
    unsigned short b = f2bf(w[i]);
    if (k < 256) wt_h[n * 256 + k] = b;
    else         wt_e[n * 64 + (k - 256)] = b;
}

// ---------------- MFMA GEMM: out[M x 256] = A[M x K](bf16) @ Wt[256 x K](bf16, n-major) ----
// 128x128 block tile, 4 waves (2x2), each wave 4x4 frags of 16x16x32_bf16.
// Verified layouts: A/B operand [dim=lane&15][k=quad*8+j]; C/D col=lane&15, row=quad*4+reg.

#define GTM 128
#define GBK 64
#define ALD 72   // row stride in bf16 (64 + 8 pad; 144B = 9*16B keeps alignment, breaks conflicts)

template<int OUT_F32>
__global__ __launch_bounds__(256) void k_gemm_mfma(const unsigned short* __restrict__ A,
                                                   int M, int K,
                                                   const unsigned short* __restrict__ Wt,
                                                   void* __restrict__ out) {
    __shared__ unsigned short As[GTM * ALD];
    __shared__ unsigned short Bs[GTM * ALD];
    int m0 = blockIdx.y * GTM;
    int n0 = blockIdx.x * GTM;
    int t = threadIdx.x;
    int wave = t >> 6, lane = t & 63;
    int wy = wave >> 1, wx = wave & 1;
    int quad = lane >> 4, l16 = lane & 15;

    f32x4 acc[4][4];
#pragma unroll
    for (int i = 0; i < 4; i++)
#pragma unroll
        for (int j = 0; j < 4; j++) acc[i][j] = (f32x4){0.f, 0.f, 0.f, 0.f};

    for (int k0 = 0; k0 < K; k0 += GBK) {
#pragma unroll
        for (int q = 0; q < 4; q++) {
            int idx = t + q * 256;
            int row = idx >> 3;
            int c16 = idx & 7;
            int gm = m0 + row;
            uint4 v = make_uint4(0, 0, 0, 0);
            if (gm < M) v = *(const uint4*)&A[(size_t)gm * K + k0 + c16 * 8];
            *(uint4*)&As[row * ALD + c16 * 8] = v;
        }
#pragma unroll
        for (int q = 0; q < 4; q++) {
            int idx = t + q * 256;
            int row = idx >> 3;
            int c16 = idx & 7;
            uint4 v = *(const uint4*)&Wt[(size_t)(n0 + row) * K + k0 + c16 * 8];
            *(uint4*)&Bs[row * ALD + c16 * 8] = v;
        }
        __syncthreads();
#pragma unroll
        for (int kk = 0; kk < GBK / 32; kk++) {
            short8 af[4], bf[4];
#pragma unroll
            for (int i = 0; i < 4; i++) {
                af[i] = *(const short8*)&As[(wy * 64 + i * 16 + l16) * ALD + kk * 32 + quad * 8];
                bf[i] = *(const short8*)&Bs[(wx * 64 + i * 16 + l16) * ALD + kk * 32 + quad * 8];
            }
#pragma unroll
            for (int i = 0; i < 4; i++)
#pragma unroll
                for (int j = 0; j < 4; j++)
                    acc[i][j] = __builtin_amdgcn_mfma_f32_16x16x32_bf16(af[i], bf[j], acc[i][j], 0, 0, 0);
        }
        __syncthreads();
    }

#pragma unroll
    for (int i = 0; i < 4; i++)
#pragma unroll
        for (int j = 0; j < 4; j++)
#pragma unroll
            for (int r = 0; r < 4; r++) {
                int gm = m0 + wy * 64 + i * 16 + quad * 4 + r;
                int gn = n0 + wx * 64 + j * 16 + l16;
                if (gm < M) {
                    float v = acc[i][j][r];
                    if (OUT_F32) ((float*)out)[(size_t)gm * FOUT + gn] = v;
                    else ((unsigned short*)out)[(size_t)gm * FOUT + gn] = f2bf(v);
                }
            }
}

// ---------------- edge aggregation: CSR gather, unroll-8, bf16 output ----------------

__global__ __launch_bounds__(256) void k_agg_e(const float* __restrict__ edge_feat,
                                               const int* __restrict__ row_ptr,
                                               const int* __restrict__ s_eid,
                                               unsigned short* __restrict__ agg_eb, int N) {
    int w = threadIdx.x >> 6;
    int lane = threadIdx.x & 63;
    int n = blockIdx.x * 4 + w;
    if (n >= N) return;
    int beg = row_ptr[n], end = row_ptr[n + 1];
    float acc = 0.f;
    int p = beg;
    for (; p + 8 <= end; p += 8) {
        int e0 = s_eid[p + 0], e1 = s_eid[p + 1], e2 = s_eid[p + 2], e3 = s_eid[p + 3];
        int e4 = s_eid[p + 4], e5 = s_eid[p + 5], e6 = s_eid[p + 6], e7 = s_eid[p + 7];
        float v0 = edge_feat[(size_t)e0 * FE + lane];
        float v1 = edge_feat[(size_t)e1 * FE + lane];
        float v2 = edge_feat[(size_t)e2 * FE + lane];
        float v3 = edge_feat[(size_t)e3 * FE + lane];
        float v4 = edge_feat[(size_t)e4 * FE + lane];
        float v5 = edge_feat[(size_t)e5 * FE + lane];
        float v6 = edge_feat[(size_t)e6 * FE + lane];
        float v7 = edge_feat[(size_t)e7 * FE + lane];
        acc += ((v0 + v1) + (v2 + v3)) + ((v4 + v5) + (v6 + v7));
    }
    for (; p < end; p++) acc += edge_feat[(size_t)s_eid[p] * FE + lane];
    agg_eb[(size_t)n * FE + lane] = f2bf(acc);
}

// ---------------- final: out[n] = relu(norm_in[n]*(h2[n] + sum gb[src]) + bias) ----
// gb is bf16 [N,256]; h2 staged f32 in d_out. 4 waves/node, unroll-8 prefetch.

__global__ __launch_bounds__(256) void k_final(const unsigned short* __restrict__ gb,
                                               const float* __restrict__ bias,
                                               const int* __restrict__ row_ptr,
                                               const int* __restrict__ s_src,
                                               const float* __restrict__ norm_in,
                                               float* __restrict__ out, int N) {
    int w = threadIdx.x >> 6;
    int lane = threadIdx.x & 63;
    int n = blockIdx.x;
    if (n >= N) return;
    int c = w * 64 + lane;
    int beg = row_ptr[n], end = row_ptr[n + 1];
    float acc = out[(size_t)n * FOUT + c];
    int p = beg;
    for (; p + 8 <= end; p += 8) {
        int s0 = s_src[p + 0], s1 = s_src[p + 1], s2 = s_src[p + 2], s3 = s_src[p + 3];
        int s4 = s_src[p + 4], s5 = s_src[p + 5], s6 = s_src[p + 6], s7 = s_src[p + 7];
        float g0 = bf2f(gb[(size_t)s0 * FOUT + c]);
        float g1 = bf2f(gb[(size_t)s1 * FOUT + c]);
        float g2 = bf2f(gb[(size_t)s2 * FOUT + c]);
        float g3 = bf2f(gb[(size_t)s3 * FOUT + c]);
        float g4 = bf2f(gb[(size_t)s4 * FOUT + c]);
        float g5 = bf2f(gb[(size_t)s5 * FOUT + c]);
        float g6 = bf2f(gb[(size_t)s6 * FOUT + c]);
        float g7 = bf2f(gb[(size_t)s7 * FOUT + c]);
        acc += ((g0 + g1) + (g2 + g3)) + ((g4 + g5) + (g6 + g7));
    }
    for (; p < end; p++) acc += bf2f(gb[(size_t)s_src[p] * FOUT + c]);
    float ni = norm_in[n];
    float o = fmaxf(acc * ni + bias[c], 0.f);
    out[(size_t)n * FOUT + c] = o;
}

// ---------------- launch ----------------

extern "C" void kernel_launch(void* const* d_in, const int* in_sizes, int n_in,
                              void* d_out, int out_size, void* d_ws, size_t ws_size,
                              hipStream_t stream) {
    const float* feat      = (const float*)d_in[0];
    const float* edge_feat = (const float*)d_in[1];
    const float* weight    = (const float*)d_in[2];
    const float* bias      = (const float*)d_in[3];
    const int*   src       = (const int*)d_in[4];
    const int*   dst       = (const int*)d_in[5];
    int E = in_sizes[4];
    int N = in_sizes[0] / FIN;

    char* ws = (char*)d_ws;
    size_t off = 0;
    auto alloc = [&](size_t bytes) -> void* {
        void* p = ws + off;
        off += (bytes + 255) & ~(size_t)255;
        return p;
    };
    unsigned short* gb      = (unsigned short*)alloc((size_t)N * FOUT * 2);  // 25.6 MB
    unsigned short* featb   = (unsigned short*)alloc((size_t)N * FIN * 2);   // 25.6 MB
    unsigned short* agg_eb  = (unsigned short*)alloc((size_t)N * FE * 2);    // 6.4 MB
    unsigned short* wt_h    = (unsigned short*)alloc((size_t)FOUT * FIN * 2);
    unsigned short* wt_e    = (unsigned short*)alloc((size_t)FOUT * FE * 2);
    int*   out_deg  = (int*)alloc((size_t)N * 4);
    int*   in_deg   = (int*)alloc((size_t)N * 4);
    int*   row_ptr  = (int*)alloc((size_t)(N + 1) * 4);
    int*   cursor   = (int*)alloc((size_t)N * 4);
    float* norm_out = (float*)alloc((size_t)N * 4);
    float* norm_in  = (float*)alloc((size_t)N * 4);
    int*   s_src    = (int*)alloc((size_t)E * 4);
    int*   s_eid    = (int*)alloc((size_t)E * 4);
    (void)ws_size;

    int bE = (E + 255) / 256;
    int nchunk = (N + 1023) >> 10;

    hipMemsetAsync(out_deg, 0, (size_t)N * 4, stream);
    hipMemsetAsync(in_deg, 0, (size_t)N * 4, stream);

    k_deg<<<bE, 256, 0, stream>>>(src, dst, out_deg, in_deg, E);
    k_scan<<<nchunk, 1024, 0, stream>>>(in_deg, row_ptr, cursor, N);
    k_norm<<<(N + 255) / 256, 256, 0, stream>>>(out_deg, in_deg, norm_out, norm_in, N);
    k_scatter<<<bE, 256, 0, stream>>>(src, dst, cursor, s_src, s_eid, E);

    // bf16 prep
    k_prep_w<<<(320 * 256 + 255) / 256, 256, 0, stream>>>(weight, wt_h, wt_e);
    k_prep_feat<<<(N * 64 + 255) / 256, 256, 0, stream>>>(feat, norm_out, featb, N);

    // GEMM1: gb = featb @ W_h  (bf16 in, bf16 out)
    dim3 gg(FOUT / GTM, (N + GTM - 1) / GTM);
    k_gemm_mfma<0><<<gg, 256, 0, stream>>>(featb, N, FIN, wt_h, gb);

    // edge aggregation (bf16 out)
    k_agg_e<<<(N + 3) / 4, 256, 0, stream>>>(edge_feat, row_ptr, s_eid, agg_eb, N);

    // GEMM2: h2 = agg_eb @ W_e -> f32 into d_out
    k_gemm_mfma<1><<<gg, 256, 0, stream>>>(agg_eb, N, FE, wt_e, d_out);

    // final: gather gb rows per dst, add h2, normalize, bias, relu
    k_final<<<N, 256, 0, stream>>>(gb, bias, row_ptr, s_src, norm_in, (float*)d_out, N);
}

// Round 5
// 524.433 us; speedup vs baseline: 1.6744x; 1.1450x over previous
//
#include <hip/hip_runtime.h>

#define FIN 256
#define FE  64
#define FOUT 256
#define KTOT 320   // FIN + FE

typedef __attribute__((ext_vector_type(8))) short short8;
typedef __attribute__((ext_vector_type(4))) float f32x4;

__device__ inline unsigned short f2bf(float f) {  // RNE
    unsigned int u = __builtin_bit_cast(unsigned int, f);
    u += 0x7fffu + ((u >> 16) & 1u);
    return (unsigned short)(u >> 16);
}

// ---------------- CSR build ----------------

__global__ void k_deg(const int* __restrict__ src, const int* __restrict__ dst,
                      int* __restrict__ out_deg, int* __restrict__ in_deg, int E) {
    int i = blockIdx.x * blockDim.x + threadIdx.x;
    if (i < E) {
        atomicAdd(&out_deg[src[i]], 1);
        atomicAdd(&in_deg[dst[i]], 1);
    }
}

// scan-free multi-block exclusive scan: block b redundantly sums in_deg[0..b*1024)
__global__ __launch_bounds__(1024) void k_scan(const int* __restrict__ in_deg,
                                               int* __restrict__ row_ptr,
                                               int* __restrict__ cursor, int N) {
    __shared__ int red[16];
    __shared__ int wsum[16];
    __shared__ int wo[17];
    int b = blockIdx.x, t = threadIdx.x;
    int lane = t & 63, w = t >> 6;
    int limit = b << 10;

    int part = 0;
    for (int i = t; i < limit; i += 1024) part += in_deg[i];
#pragma unroll
    for (int off = 32; off; off >>= 1) part += __shfl_down(part, off, 64);
    if (lane == 0) red[w] = part;
    __syncthreads();
    if (t == 0) {
        int s = 0;
#pragma unroll
        for (int k = 0; k < 16; k++) s += red[k];
        red[0] = s;
    }
    __syncthreads();
    int base = red[0];

    int i = limit + t;
    int v = (i < N) ? in_deg[i] : 0;
    int incl = v;
#pragma unroll
    for (int off = 1; off < 64; off <<= 1) {
        int x = __shfl_up(incl, off, 64);
        if (lane >= off) incl += x;
    }
    if (lane == 63) wsum[w] = incl;
    __syncthreads();
    if (w == 0 && lane < 16) {
        int s = wsum[lane];
        int sc = s;
#pragma unroll
        for (int off = 1; off < 16; off <<= 1) {
            int x = __shfl_up(sc, off, 64);
            if (lane >= off) sc += x;
        }
        wo[lane] = sc - s;
        if (lane == 15) wo[16] = sc;
    }
    __syncthreads();
    int excl = base + wo[w] + incl - v;
    if (i < N) { row_ptr[i] = excl; cursor[i] = excl; }
    if (t == 0 && i + 1024 > N && i < N + 1024) row_ptr[N] = base + wo[16];
}

__global__ void k_norm(const int* __restrict__ out_deg, const int* __restrict__ in_deg,
                       float* __restrict__ norm_out, float* __restrict__ norm_in, int N) {
    int i = blockIdx.x * blockDim.x + threadIdx.x;
    if (i < N) {
        norm_out[i] = 1.0f / sqrtf((float)max(out_deg[i], 1));
        norm_in[i]  = 1.0f / sqrtf((float)max(in_deg[i], 1));
    }
}

// one int2 (src, eid) per CSR slot — single 8B scatter write per edge
__global__ void k_scatter(const int* __restrict__ src, const int* __restrict__ dst,
                          int* __restrict__ cursor, int2* __restrict__ s_se, int E) {
    int i = blockIdx.x * blockDim.x + threadIdx.x;
    if (i < E) {
        int d = dst[i];
        int p = atomicAdd(&cursor[d], 1);
        s_se[p] = make_int2(src[i], i);
    }
}

// ---------------- bf16 prep passes ----------------

__global__ void k_prep_feat(const float* __restrict__ feat, const float* __restrict__ norm_out,
                            unsigned short* __restrict__ featb, int N) {
    int i = blockIdx.x * 256 + threadIdx.x;
    if (i >= N * 64) return;
    int m = i >> 6, c4 = (i & 63) * 4;
    float s = norm_out[m];
    float4 v = *(const float4*)&feat[(size_t)m * FIN + c4];
    ushort4 o;
    o.x = f2bf(v.x * s); o.y = f2bf(v.y * s); o.z = f2bf(v.z * s); o.w = f2bf(v.w * s);
    *(ushort4*)&featb[(size_t)m * FIN + c4] = o;
}

// weight [320 k][256 n] f32 -> wtt [256 n][320 k] bf16 (n-major for MFMA B-operand)
__global__ void k_prep_w(const float* __restrict__ w, unsigned short* __restrict__ wtt) {
    int i = blockIdx.x * 256 + threadIdx.x;
    if (i >= KTOT * 256) return;
    int k = i >> 8, n = i & 255;
    wtt[n * KTOT + k] = f2bf(w[i]);
}

// ---------------- fused CSR gather: aggb[n] = [sum featb[src], bf16(sum edge_feat[eid])] ----
// one wave per node. Lane l: featb channels 4l..4l+3 (ushort4, coalesced 512B/row),
// edge_feat channel l (f32, coalesced 256B/row). Unroll-4 index prefetch via int2.

__global__ __launch_bounds__(256) void k_agg(const unsigned short* __restrict__ featb,
                                             const float* __restrict__ edge_feat,
                                             const int* __restrict__ row_ptr,
                                             const int2* __restrict__ s_se,
                                             unsigned short* __restrict__ aggb, int N) {
    int w = threadIdx.x >> 6;
    int lane = threadIdx.x & 63;
    int n = blockIdx.x * 4 + w;
    if (n >= N) return;
    int beg = row_ptr[n], end = row_ptr[n + 1];
    float h0 = 0.f, h1 = 0.f, h2 = 0.f, h3 = 0.f, eacc = 0.f;
    int p = beg;
    for (; p + 4 <= end; p += 4) {
        int2 a = s_se[p + 0], b = s_se[p + 1], c = s_se[p + 2], d = s_se[p + 3];
        ushort4 f0 = *(const ushort4*)&featb[(size_t)a.x * FIN + lane * 4];
        ushort4 f1 = *(const ushort4*)&featb[(size_t)b.x * FIN + lane * 4];
        ushort4 f2 = *(const ushort4*)&featb[(size_t)c.x * FIN + lane * 4];
        ushort4 f3 = *(const ushort4*)&featb[(size_t)d.x * FIN + lane * 4];
        float e0 = edge_feat[(size_t)a.y * FE + lane];
        float e1 = edge_feat[(size_t)b.y * FE + lane];
        float e2 = edge_feat[(size_t)c.y * FE + lane];
        float e3 = edge_feat[(size_t)d.y * FE + lane];
        h0 += __builtin_bit_cast(float, (unsigned)f0.x << 16) + __builtin_bit_cast(float, (unsigned)f1.x << 16)
            + __builtin_bit_cast(float, (unsigned)f2.x << 16) + __builtin_bit_cast(float, (unsigned)f3.x << 16);
        h1 += __builtin_bit_cast(float, (unsigned)f0.y << 16) + __builtin_bit_cast(float, (unsigned)f1.y << 16)
            + __builtin_bit_cast(float, (unsigned)f2.y << 16) + __builtin_bit_cast(float, (unsigned)f3.y << 16);
        h2 += __builtin_bit_cast(float, (unsigned)f0.z << 16) + __builtin_bit_cast(float, (unsigned)f1.z << 16)
            + __builtin_bit_cast(float, (unsigned)f2.z << 16) + __builtin_bit_cast(float, (unsigned)f3.z << 16);
        h3 += __builtin_bit_cast(float, (unsigned)f0.w << 16) + __builtin_bit_cast(float, (unsigned)f1.w << 16)
            + __builtin_bit_cast(float, (unsigned)f2.w << 16) + __builtin_bit_cast(float, (unsigned)f3.w << 16);
        eacc += (e0 + e1) + (e2 + e3);
    }
    for (; p < end; p++) {
        int2 a = s_se[p];
        ushort4 f0 = *(const ushort4*)&featb[(size_t)a.x * FIN + lane * 4];
        h0 += __builtin_bit_cast(float, (unsigned)f0.x << 16);
        h1 += __builtin_bit_cast(float, (unsigned)f0.y << 16);
        h2 += __builtin_bit_cast(float, (unsigned)f0.z << 16);
        h3 += __builtin_bit_cast(float, (unsigned)f0.w << 16);
        eacc += edge_feat[(size_t)a.y * FE + lane];
    }
    ushort4 o;
    o.x = f2bf(h0); o.y = f2bf(h1); o.z = f2bf(h2); o.w = f2bf(h3);
    *(ushort4*)&aggb[(size_t)n * KTOT + lane * 4] = o;            // channels 0..255
    aggb[(size_t)n * KTOT + FIN + lane] = f2bf(eacc);             // channels 256..319
}

// ---------------- MFMA GEMM K=320 with fused epilogue: out = relu(norm_in*(A@Wt) + bias) ----
// 128x128 tile, 4 waves (2x2), 4x4 frags of 16x16x32_bf16.
// A/B operand [dim=lane&15][k=quad*8+j]; C/D col=lane&15, row=quad*4+reg.

#define GTM 128
#define GBK 64
#define ALD 72   // LDS row stride in bf16 (64+8 pad)

__global__ __launch_bounds__(256) void k_gemm_fused(const unsigned short* __restrict__ A,
                                                    int M,
                                                    const unsigned short* __restrict__ Wt,
                                                    const float* __restrict__ norm_in,
                                                    const float* __restrict__ bias,
                                                    float* __restrict__ out) {
    __shared__ unsigned short As[GTM * ALD];
    __shared__ unsigned short Bs[GTM * ALD];
    int m0 = blockIdx.y * GTM;
    int n0 = blockIdx.x * GTM;
    int t = threadIdx.x;
    int wave = t >> 6, lane = t & 63;
    int wy = wave >> 1, wx = wave & 1;
    int quad = lane >> 4, l16 = lane & 15;

    f32x4 acc[4][4];
#pragma unroll
    for (int i = 0; i < 4; i++)
#pragma unroll
        for (int j = 0; j < 4; j++) acc[i][j] = (f32x4){0.f, 0.f, 0.f, 0.f};

    for (int k0 = 0; k0 < KTOT; k0 += GBK) {
#pragma unroll
        for (int q = 0; q < 4; q++) {
            int idx = t + q * 256;
            int row = idx >> 3;
            int c16 = idx & 7;
            int gm = m0 + row;
            uint4 v = make_uint4(0, 0, 0, 0);
            if (gm < M) v = *(const uint4*)&A[(size_t)gm * KTOT + k0 + c16 * 8];
            *(uint4*)&As[row * ALD + c16 * 8] = v;
        }
#pragma unroll
        for (int q = 0; q < 4; q++) {
            int idx = t + q * 256;
            int row = idx >> 3;
            int c16 = idx & 7;
            uint4 v = *(const uint4*)&Wt[(size_t)(n0 + row) * KTOT + k0 + c16 * 8];
            *(uint4*)&Bs[row * ALD + c16 * 8] = v;
        }
        __syncthreads();
#pragma unroll
        for (int kk = 0; kk < GBK / 32; kk++) {
            short8 af[4], bf[4];
#pragma unroll
            for (int i = 0; i < 4; i++) {
                af[i] = *(const short8*)&As[(wy * 64 + i * 16 + l16) * ALD + kk * 32 + quad * 8];
                bf[i] = *(const short8*)&Bs[(wx * 64 + i * 16 + l16) * ALD + kk * 32 + quad * 8];
            }
#pragma unroll
            for (int i = 0; i < 4; i++)
#pragma unroll
                for (int j = 0; j < 4; j++)
                    acc[i][j] = __builtin_amdgcn_mfma_f32_16x16x32_bf16(af[i], bf[j], acc[i][j], 0, 0, 0);
        }
        __syncthreads();
    }

#pragma unroll
    for (int i = 0; i < 4; i++)
#pragma unroll
        for (int r = 0; r < 4; r++) {
            int gm = m0 + wy * 64 + i * 16 + quad * 4 + r;
            if (gm < M) {
                float ni = norm_in[gm];
#pragma unroll
                for (int j = 0; j < 4; j++) {
                    int gn = n0 + wx * 64 + j * 16 + l16;
                    float v = fmaxf(acc[i][j][r] * ni + bias[gn], 0.f);
                    out[(size_t)gm * FOUT + gn] = v;
                }
            }
        }
}

// ---------------- launch ----------------

extern "C" void kernel_launch(void* const* d_in, const int* in_sizes, int n_in,
                              void* d_out, int out_size, void* d_ws, size_t ws_size,
                              hipStream_t stream) {
    const float* feat      = (const float*)d_in[0];
    const float* edge_feat = (const float*)d_in[1];
    const float* weight    = (const float*)d_in[2];
    const float* bias      = (const float*)d_in[3];
    const int*   src       = (const int*)d_in[4];
    const int*   dst       = (const int*)d_in[5];
    int E = in_sizes[4];
    int N = in_sizes[0] / FIN;

    char* ws = (char*)d_ws;
    size_t off = 0;
    auto alloc = [&](size_t bytes) -> void* {
        void* p = ws + off;
        off += (bytes + 255) & ~(size_t)255;
        return p;
    };
    unsigned short* featb = (unsigned short*)alloc((size_t)N * FIN * 2);    // 25.6 MB
    unsigned short* aggb  = (unsigned short*)alloc((size_t)N * KTOT * 2);   // 32 MB
    unsigned short* wtt   = (unsigned short*)alloc((size_t)256 * KTOT * 2);
    int*   out_deg  = (int*)alloc((size_t)N * 4);
    int*   in_deg   = (int*)alloc((size_t)N * 4);
    int*   row_ptr  = (int*)alloc((size_t)(N + 1) * 4);
    int*   cursor   = (int*)alloc((size_t)N * 4);
    float* norm_out = (float*)alloc((size_t)N * 4);
    float* norm_in  = (float*)alloc((size_t)N * 4);
    int2*  s_se     = (int2*)alloc((size_t)E * 8);
    (void)ws_size;

    int bE = (E + 255) / 256;
    int nchunk = (N + 1023) >> 10;

    hipMemsetAsync(out_deg, 0, (size_t)N * 4, stream);
    hipMemsetAsync(in_deg, 0, (size_t)N * 4, stream);

    k_deg<<<bE, 256, 0, stream>>>(src, dst, out_deg, in_deg, E);
    k_scan<<<nchunk, 1024, 0, stream>>>(in_deg, row_ptr, cursor, N);
    k_norm<<<(N + 255) / 256, 256, 0, stream>>>(out_deg, in_deg, norm_out, norm_in, N);
    k_scatter<<<bE, 256, 0, stream>>>(src, dst, cursor, s_se, E);

    k_prep_w<<<(KTOT * 256 + 255) / 256, 256, 0, stream>>>(weight, wtt);
    k_prep_feat<<<(N * 64 + 255) / 256, 256, 0, stream>>>(feat, norm_out, featb, N);

    // fused aggregation: aggb[n] = [sum featb[src], sum edge_feat[eid]] (bf16)
    k_agg<<<(N + 3) / 4, 256, 0, stream>>>(featb, edge_feat, row_ptr, s_se, aggb, N);

    // fused GEMM + epilogue: out = relu(norm_in * (aggb @ Wt) + bias)
    dim3 gg(FOUT / GTM, (N + GTM - 1) / GTM);
    k_gemm_fused<<<gg, 256, 0, stream>>>(aggb, N, wtt, norm_in, bias, (float*)d_out);
}

// Round 6
// 523.447 us; speedup vs baseline: 1.6776x; 1.0019x over previous
//
#include <hip/hip_runtime.h>

#define FIN 256
#define FE  64
#define FOUT 256
#define KTOT 320   // FIN + FE

typedef __attribute__((ext_vector_type(8))) short short8;
typedef __attribute__((ext_vector_type(4))) float f32x4;

__device__ inline unsigned short f2bf(float f) {  // RNE
    unsigned int u = __builtin_bit_cast(unsigned int, f);
    u += 0x7fffu + ((u >> 16) & 1u);
    return (unsigned short)(u >> 16);
}
__device__ inline float bfu(unsigned short b) {
    return __builtin_bit_cast(float, (unsigned int)b << 16);
}

// ---------------- CSR build ----------------

__global__ void k_deg(const int* __restrict__ src, const int* __restrict__ dst,
                      int* __restrict__ out_deg, int* __restrict__ in_deg, int E) {
    int i = blockIdx.x * blockDim.x + threadIdx.x;
    if (i < E) {
        atomicAdd(&out_deg[src[i]], 1);
        atomicAdd(&in_deg[dst[i]], 1);
    }
}

// scan-free multi-block exclusive scan + fused degree-norm computation.
// block b redundantly sums in_deg[0..b*1024), then shuffle-scans its chunk.
__global__ __launch_bounds__(1024) void k_scan(const int* __restrict__ in_deg,
                                               const int* __restrict__ out_deg,
                                               int* __restrict__ row_ptr,
                                               int* __restrict__ cursor,
                                               float* __restrict__ norm_out,
                                               float* __restrict__ norm_in, int N) {
    __shared__ int red[16];
    __shared__ int wsum[16];
    __shared__ int wo[17];
    int b = blockIdx.x, t = threadIdx.x;
    int lane = t & 63, w = t >> 6;
    int limit = b << 10;

    int part = 0;
    for (int i = t; i < limit; i += 1024) part += in_deg[i];
#pragma unroll
    for (int off = 32; off; off >>= 1) part += __shfl_down(part, off, 64);
    if (lane == 0) red[w] = part;
    __syncthreads();
    if (t == 0) {
        int s = 0;
#pragma unroll
        for (int k = 0; k < 16; k++) s += red[k];
        red[0] = s;
    }
    __syncthreads();
    int base = red[0];

    int i = limit + t;
    int v = (i < N) ? in_deg[i] : 0;
    int incl = v;
#pragma unroll
    for (int off = 1; off < 64; off <<= 1) {
        int x = __shfl_up(incl, off, 64);
        if (lane >= off) incl += x;
    }
    if (lane == 63) wsum[w] = incl;
    __syncthreads();
    if (w == 0 && lane < 16) {
        int s = wsum[lane];
        int sc = s;
#pragma unroll
        for (int off = 1; off < 16; off <<= 1) {
            int x = __shfl_up(sc, off, 64);
            if (lane >= off) sc += x;
        }
        wo[lane] = sc - s;
        if (lane == 15) wo[16] = sc;
    }
    __syncthreads();
    int excl = base + wo[w] + incl - v;
    if (i < N) {
        row_ptr[i] = excl;
        cursor[i] = excl;
        norm_in[i]  = 1.0f / sqrtf((float)max(v, 1));
        norm_out[i] = 1.0f / sqrtf((float)max(out_deg[i], 1));
    }
    if (t == 0 && i + 1024 > N && i < N + 1024) row_ptr[N] = base + wo[16];
}

// one int2 (src, eid) per CSR slot — single 8B scatter write per edge
__global__ void k_scatter(const int* __restrict__ src, const int* __restrict__ dst,
                          int* __restrict__ cursor, int2* __restrict__ s_se, int E) {
    int i = blockIdx.x * blockDim.x + threadIdx.x;
    if (i < E) {
        int d = dst[i];
        int p = atomicAdd(&cursor[d], 1);
        s_se[p] = make_int2(src[i], i);
    }
}

// ---------------- bf16 prep passes ----------------

__global__ void k_prep_feat(const float* __restrict__ feat, const float* __restrict__ norm_out,
                            unsigned short* __restrict__ featb, int N) {
    int i = blockIdx.x * 256 + threadIdx.x;
    if (i >= N * 64) return;
    int m = i >> 6, c4 = (i & 63) * 4;
    float s = norm_out[m];
    float4 v = *(const float4*)&feat[(size_t)m * FIN + c4];
    ushort4 o;
    o.x = f2bf(v.x * s); o.y = f2bf(v.y * s); o.z = f2bf(v.z * s); o.w = f2bf(v.w * s);
    *(ushort4*)&featb[(size_t)m * FIN + c4] = o;
}

// weight [320 k][256 n] f32 -> wtt [256 n][320 k] bf16 (n-major for MFMA B-operand)
__global__ void k_prep_w(const float* __restrict__ w, unsigned short* __restrict__ wtt) {
    int i = blockIdx.x * 256 + threadIdx.x;
    if (i >= KTOT * 256) return;
    int k = i >> 8, n = i & 255;
    wtt[n * KTOT + k] = f2bf(w[i]);
}

// ---------------- fused CSR gather: aggb[n] = [sum featb[src], bf16(sum edge_feat[eid])] ----
// one wave per node. Lane l: featb channels 4l..4l+3 (ushort4, 512B/row coalesced),
// edge_feat channel l (f32, 256B/row coalesced, NON-TEMPORAL: touched once, keep out
// of L2/L3 so the hot 25.6MB featb stays resident). Unroll-8 -> 16 gathers in flight.

__global__ __launch_bounds__(256) void k_agg(const unsigned short* __restrict__ featb,
                                             const float* __restrict__ edge_feat,
                                             const int* __restrict__ row_ptr,
                                             const int2* __restrict__ s_se,
                                             unsigned short* __restrict__ aggb, int N) {
    int w = threadIdx.x >> 6;
    int lane = threadIdx.x & 63;
    int n = blockIdx.x * 4 + w;
    if (n >= N) return;
    int beg = row_ptr[n], end = row_ptr[n + 1];
    float h0 = 0.f, h1 = 0.f, h2 = 0.f, h3 = 0.f, eacc = 0.f;
    int p = beg;
    for (; p + 8 <= end; p += 8) {
        int2 i0 = s_se[p + 0], i1 = s_se[p + 1], i2 = s_se[p + 2], i3 = s_se[p + 3];
        int2 i4 = s_se[p + 4], i5 = s_se[p + 5], i6 = s_se[p + 6], i7 = s_se[p + 7];
        ushort4 f0 = *(const ushort4*)&featb[(size_t)i0.x * FIN + lane * 4];
        ushort4 f1 = *(const ushort4*)&featb[(size_t)i1.x * FIN + lane * 4];
        ushort4 f2 = *(const ushort4*)&featb[(size_t)i2.x * FIN + lane * 4];
        ushort4 f3 = *(const ushort4*)&featb[(size_t)i3.x * FIN + lane * 4];
        ushort4 f4 = *(const ushort4*)&featb[(size_t)i4.x * FIN + lane * 4];
        ushort4 f5 = *(const ushort4*)&featb[(size_t)i5.x * FIN + lane * 4];
        ushort4 f6 = *(const ushort4*)&featb[(size_t)i6.x * FIN + lane * 4];
        ushort4 f7 = *(const ushort4*)&featb[(size_t)i7.x * FIN + lane * 4];
        float e0 = __builtin_nontemporal_load(&edge_feat[(size_t)i0.y * FE + lane]);
        float e1 = __builtin_nontemporal_load(&edge_feat[(size_t)i1.y * FE + lane]);
        float e2 = __builtin_nontemporal_load(&edge_feat[(size_t)i2.y * FE + lane]);
        float e3 = __builtin_nontemporal_load(&edge_feat[(size_t)i3.y * FE + lane]);
        float e4 = __builtin_nontemporal_load(&edge_feat[(size_t)i4.y * FE + lane]);
        float e5 = __builtin_nontemporal_load(&edge_feat[(size_t)i5.y * FE + lane]);
        float e6 = __builtin_nontemporal_load(&edge_feat[(size_t)i6.y * FE + lane]);
        float e7 = __builtin_nontemporal_load(&edge_feat[(size_t)i7.y * FE + lane]);
        h0 += (bfu(f0.x) + bfu(f1.x)) + (bfu(f2.x) + bfu(f3.x))
            + (bfu(f4.x) + bfu(f5.x)) + (bfu(f6.x) + bfu(f7.x));
        h1 += (bfu(f0.y) + bfu(f1.y)) + (bfu(f2.y) + bfu(f3.y))
            + (bfu(f4.y) + bfu(f5.y)) + (bfu(f6.y) + bfu(f7.y));
        h2 += (bfu(f0.z) + bfu(f1.z)) + (bfu(f2.z) + bfu(f3.z))
            + (bfu(f4.z) + bfu(f5.z)) + (bfu(f6.z) + bfu(f7.z));
        h3 += (bfu(f0.w) + bfu(f1.w)) + (bfu(f2.w) + bfu(f3.w))
            + (bfu(f4.w) + bfu(f5.w)) + (bfu(f6.w) + bfu(f7.w));
        eacc += ((e0 + e1) + (e2 + e3)) + ((e4 + e5) + (e6 + e7));
    }
    for (; p + 4 <= end; p += 4) {
        int2 i0 = s_se[p + 0], i1 = s_se[p + 1], i2 = s_se[p + 2], i3 = s_se[p + 3];
        ushort4 f0 = *(const ushort4*)&featb[(size_t)i0.x * FIN + lane * 4];
        ushort4 f1 = *(const ushort4*)&featb[(size_t)i1.x * FIN + lane * 4];
        ushort4 f2 = *(const ushort4*)&featb[(size_t)i2.x * FIN + lane * 4];
        ushort4 f3 = *(const ushort4*)&featb[(size_t)i3.x * FIN + lane * 4];
        float e0 = __builtin_nontemporal_load(&edge_feat[(size_t)i0.y * FE + lane]);
        float e1 = __builtin_nontemporal_load(&edge_feat[(size_t)i1.y * FE + lane]);
        float e2 = __builtin_nontemporal_load(&edge_feat[(size_t)i2.y * FE + lane]);
        float e3 = __builtin_nontemporal_load(&edge_feat[(size_t)i3.y * FE + lane]);
        h0 += (bfu(f0.x) + bfu(f1.x)) + (bfu(f2.x) + bfu(f3.x));
        h1 += (bfu(f0.y) + bfu(f1.y)) + (bfu(f2.y) + bfu(f3.y));
        h2 += (bfu(f0.z) + bfu(f1.z)) + (bfu(f2.z) + bfu(f3.z));
        h3 += (bfu(f0.w) + bfu(f1.w)) + (bfu(f2.w) + bfu(f3.w));
        eacc += (e0 + e1) + (e2 + e3);
    }
    for (; p < end; p++) {
        int2 a = s_se[p];
        ushort4 f0 = *(const ushort4*)&featb[(size_t)a.x * FIN + lane * 4];
        h0 += bfu(f0.x); h1 += bfu(f0.y); h2 += bfu(f0.z); h3 += bfu(f0.w);
        eacc += __builtin_nontemporal_load(&edge_feat[(size_t)a.y * FE + lane]);
    }
    ushort4 o;
    o.x = f2bf(h0); o.y = f2bf(h1); o.z = f2bf(h2); o.w = f2bf(h3);
    *(ushort4*)&aggb[(size_t)n * KTOT + lane * 4] = o;            // channels 0..255
    aggb[(size_t)n * KTOT + FIN + lane] = f2bf(eacc);             // channels 256..319
}

// ---------------- MFMA GEMM K=320 with fused epilogue: out = relu(norm_in*(A@Wt) + bias) ----
// 128x128 tile, 4 waves (2x2), 4x4 frags of 16x16x32_bf16.
// A/B operand [dim=lane&15][k=quad*8+j]; C/D col=lane&15, row=quad*4+reg.

#define GTM 128
#define GBK 64
#define ALD 72   // LDS row stride in bf16 (64+8 pad)

__global__ __launch_bounds__(256) void k_gemm_fused(const unsigned short* __restrict__ A,
                                                    int M,
                                                    const unsigned short* __restrict__ Wt,
                                                    const float* __restrict__ norm_in,
                                                    const float* __restrict__ bias,
                                                    float* __restrict__ out) {
    __shared__ unsigned short As[GTM * ALD];
    __shared__ unsigned short Bs[GTM * ALD];
    int m0 = blockIdx.y * GTM;
    int n0 = blockIdx.x * GTM;
    int t = threadIdx.x;
    int wave = t >> 6, lane = t & 63;
    int wy = wave >> 1, wx = wave & 1;
    int quad = lane >> 4, l16 = lane & 15;

    f32x4 acc[4][4];
#pragma unroll
    for (int i = 0; i < 4; i++)
#pragma unroll
        for (int j = 0; j < 4; j++) acc[i][j] = (f32x4){0.f, 0.f, 0.f, 0.f};

    for (int k0 = 0; k0 < KTOT; k0 += GBK) {
#pragma unroll
        for (int q = 0; q < 4; q++) {
            int idx = t + q * 256;
            int row = idx >> 3;
            int c16 = idx & 7;
            int gm = m0 + row;
            uint4 v = make_uint4(0, 0, 0, 0);
            if (gm < M) v = *(const uint4*)&A[(size_t)gm * KTOT + k0 + c16 * 8];
            *(uint4*)&As[row * ALD + c16 * 8] = v;
        }
#pragma unroll
        for (int q = 0; q < 4; q++) {
            int idx = t + q * 256;
            int row = idx >> 3;
            int c16 = idx & 7;
            uint4 v = *(const uint4*)&Wt[(size_t)(n0 + row) * KTOT + k0 + c16 * 8];
            *(uint4*)&Bs[row * ALD + c16 * 8] = v;
        }
        __syncthreads();
#pragma unroll
        for (int kk = 0; kk < GBK / 32; kk++) {
            short8 af[4], bf[4];
#pragma unroll
            for (int i = 0; i < 4; i++) {
                af[i] = *(const short8*)&As[(wy * 64 + i * 16 + l16) * ALD + kk * 32 + quad * 8];
                bf[i] = *(const short8*)&Bs[(wx * 64 + i * 16 + l16) * ALD + kk * 32 + quad * 8];
            }
#pragma unroll
            for (int i = 0; i < 4; i++)
#pragma unroll
                for (int j = 0; j < 4; j++)
                    acc[i][j] = __builtin_amdgcn_mfma_f32_16x16x32_bf16(af[i], bf[j], acc[i][j], 0, 0, 0);
        }
        __syncthreads();
    }

#pragma unroll
    for (int i = 0; i < 4; i++)
#pragma unroll
        for (int r = 0; r < 4; r++) {
            int gm = m0 + wy * 64 + i * 16 + quad * 4 + r;
            if (gm < M) {
                float ni = norm_in[gm];
#pragma unroll
                for (int j = 0; j < 4; j++) {
                    int gn = n0 + wx * 64 + j * 16 + l16;
                    float v = fmaxf(acc[i][j][r] * ni + bias[gn], 0.f);
                    out[(size_t)gm * FOUT + gn] = v;
                }
            }
        }
}

// ---------------- launch ----------------

extern "C" void kernel_launch(void* const* d_in, const int* in_sizes, int n_in,
                              void* d_out, int out_size, void* d_ws, size_t ws_size,
                              hipStream_t stream) {
    const float* feat      = (const float*)d_in[0];
    const float* edge_feat = (const float*)d_in[1];
    const float* weight    = (const float*)d_in[2];
    const float* bias      = (const float*)d_in[3];
    const int*   src       = (const int*)d_in[4];
    const int*   dst       = (const int*)d_in[5];
    int E = in_sizes[4];
    int N = in_sizes[0] / FIN;

    char* ws = (char*)d_ws;
    size_t off = 0;
    auto alloc = [&](size_t bytes) -> void* {
        void* p = ws + off;
        off += (bytes + 255) & ~(size_t)255;
        return p;
    };
    unsigned short* featb = (unsigned short*)alloc((size_t)N * FIN * 2);    // 25.6 MB
    unsigned short* aggb  = (unsigned short*)alloc((size_t)N * KTOT * 2);   // 32 MB
    unsigned short* wtt   = (unsigned short*)alloc((size_t)256 * KTOT * 2);
    int*   out_deg  = (int*)alloc((size_t)N * 4);
    int*   in_deg   = (int*)alloc((size_t)N * 4);
    int*   row_ptr  = (int*)alloc((size_t)(N + 1) * 4);
    int*   cursor   = (int*)alloc((size_t)N * 4);
    float* norm_out = (float*)alloc((size_t)N * 4);
    float* norm_in  = (float*)alloc((size_t)N * 4);
    int2*  s_se     = (int2*)alloc((size_t)E * 8);
    (void)ws_size;

    int bE = (E + 255) / 256;
    int nchunk = (N + 1023) >> 10;

    hipMemsetAsync(out_deg, 0, (size_t)N * 4, stream);
    hipMemsetAsync(in_deg, 0, (size_t)N * 4, stream);

    k_deg<<<bE, 256, 0, stream>>>(src, dst, out_deg, in_deg, E);
    k_scan<<<nchunk, 1024, 0, stream>>>(in_deg, out_deg, row_ptr, cursor,
                                        norm_out, norm_in, N);
    k_scatter<<<bE, 256, 0, stream>>>(src, dst, cursor, s_se, E);

    k_prep_w<<<(KTOT * 256 + 255) / 256, 256, 0, stream>>>(weight, wtt);
    k_prep_feat<<<(N * 64 + 255) / 256, 256, 0, stream>>>(feat, norm_out, featb, N);

    // fused aggregation: aggb[n] = [sum featb[src], sum edge_feat[eid]] (bf16)
    k_agg<<<(N + 3) / 4, 256, 0, stream>>>(featb, edge_feat, row_ptr, s_se, aggb, N);

    // fused GEMM + epilogue: out = relu(norm_in * (aggb @ Wt) + bias)
    dim3 gg(FOUT / GTM, (N + GTM - 1) / GTM);
    k_gemm_fused<<<gg, 256, 0, stream>>>(aggb, N, wtt, norm_in, bias, (float*)d_out);
}

// Round 8
// 505.480 us; speedup vs baseline: 1.7372x; 1.0355x over previous
//
#include <hip/hip_runtime.h>

#define FIN 256
#define FE  64
#define FOUT 256
#define KTOT 320   // FIN + FE

typedef __attribute__((ext_vector_type(8))) short short8;
typedef __attribute__((ext_vector_type(4))) float f32x4;

__device__ inline unsigned short f2bf(float f) {  // RNE
    unsigned int u = __builtin_bit_cast(unsigned int, f);
    u += 0x7fffu + ((u >> 16) & 1u);
    return (unsigned short)(u >> 16);
}
__device__ inline float bfu(unsigned short b) {
    return __builtin_bit_cast(float, (unsigned int)b << 16);
}

// ---------------- pass 1: degree histogram + weight transpose/bf16 (independent, merged) ----

__global__ void k_deg_prepw(const int* __restrict__ src, const int* __restrict__ dst,
                            int* __restrict__ out_deg, int* __restrict__ in_deg,
                            const float* __restrict__ w, unsigned short* __restrict__ wtt,
                            int E) {
    int i = blockIdx.x * blockDim.x + threadIdx.x;
    if (i < E) {
        atomicAdd(&out_deg[src[i]], 1);
        atomicAdd(&in_deg[dst[i]], 1);
    }
    if (i < KTOT * 256) {  // weight [320 k][256 n] f32 -> wtt [256 n][320 k] bf16
        int k = i >> 8, n = i & 255;
        wtt[n * KTOT + k] = f2bf(w[i]);
    }
}

// ---------------- pass 2: scan-free exclusive scan + degree norms ----------------

__global__ __launch_bounds__(1024) void k_scan(const int* __restrict__ in_deg,
                                               const int* __restrict__ out_deg,
                                               int* __restrict__ row_ptr,
                                               int* __restrict__ cursor,
                                               float* __restrict__ norm_out,
                                               float* __restrict__ norm_in, int N) {
    __shared__ int red[16];
    __shared__ int wsum[16];
    __shared__ int wo[17];
    int b = blockIdx.x, t = threadIdx.x;
    int lane = t & 63, w = t >> 6;
    int limit = b << 10;

    int part = 0;
    for (int i = t; i < limit; i += 1024) part += in_deg[i];
#pragma unroll
    for (int off = 32; off; off >>= 1) part += __shfl_down(part, off, 64);
    if (lane == 0) red[w] = part;
    __syncthreads();
    if (t == 0) {
        int s = 0;
#pragma unroll
        for (int k = 0; k < 16; k++) s += red[k];
        red[0] = s;
    }
    __syncthreads();
    int base = red[0];

    int i = limit + t;
    int v = (i < N) ? in_deg[i] : 0;
    int incl = v;
#pragma unroll
    for (int off = 1; off < 64; off <<= 1) {
        int x = __shfl_up(incl, off, 64);
        if (lane >= off) incl += x;
    }
    if (lane == 63) wsum[w] = incl;
    __syncthreads();
    if (w == 0 && lane < 16) {
        int s = wsum[lane];
        int sc = s;
#pragma unroll
        for (int off = 1; off < 16; off <<= 1) {
            int x = __shfl_up(sc, off, 64);
            if (lane >= off) sc += x;
        }
        wo[lane] = sc - s;
        if (lane == 15) wo[16] = sc;
    }
    __syncthreads();
    int excl = base + wo[w] + incl - v;
    if (i < N) {
        row_ptr[i] = excl;
        cursor[i] = excl;
        norm_in[i]  = 1.0f / sqrtf((float)max(v, 1));
        norm_out[i] = 1.0f / sqrtf((float)max(out_deg[i], 1));
    }
    if (t == 0 && i + 1024 > N && i < N + 1024) row_ptr[N] = base + wo[16];
}

// ---------------- pass 3: CSR scatter + feat->bf16 prescale (both post-scan, merged) ----

__global__ void k_scatter_prepf(const int* __restrict__ src, const int* __restrict__ dst,
                                int* __restrict__ cursor, int2* __restrict__ s_se, int E,
                                const float* __restrict__ feat,
                                const float* __restrict__ norm_out,
                                unsigned short* __restrict__ featb, int N) {
    int i = blockIdx.x * blockDim.x + threadIdx.x;
    if (i < E) {
        int d = dst[i];
        int p = atomicAdd(&cursor[d], 1);
        s_se[p] = make_int2(src[i], i);
    }
    if (i < N * 64) {
        int m = i >> 6, c4 = (i & 63) * 4;
        float s = norm_out[m];
        float4 v = *(const float4*)&feat[(size_t)m * FIN + c4];
        ushort4 o;
        o.x = f2bf(v.x * s); o.y = f2bf(v.y * s); o.z = f2bf(v.z * s); o.w = f2bf(v.w * s);
        *(ushort4*)&featb[(size_t)m * FIN + c4] = o;
    }
}

// ---------------- pass 4: fused CSR gather, 2 waves per node ----------------
// Each wave takes half the node's edge list (halves the dependent-load chain);
// LDS pairwise reduce. Lane l: featb ch 4l..4l+3 (ushort4), edge_feat ch l (f32 NT).

__global__ __launch_bounds__(256) void k_agg(const unsigned short* __restrict__ featb,
                                             const float* __restrict__ edge_feat,
                                             const int* __restrict__ row_ptr,
                                             const int2* __restrict__ s_se,
                                             unsigned short* __restrict__ aggb, int N) {
    __shared__ float red[2][5][64];
    int t = threadIdx.x;
    int w = t >> 6, lane = t & 63;
    int ln = w >> 1, sub = w & 1;        // local node [0,2), subwave [0,2)
    int n = blockIdx.x * 2 + ln;

    float h0 = 0.f, h1 = 0.f, h2 = 0.f, h3 = 0.f, eacc = 0.f;
    if (n < N) {
        int beg = row_ptr[n], end = row_ptr[n + 1];
        int half = (end - beg) >> 1;
        int p  = sub ? beg + half : beg;
        int e2 = sub ? end        : beg + half;
        for (; p + 4 <= e2; p += 4) {
            int2 i0 = s_se[p + 0], i1 = s_se[p + 1], i2 = s_se[p + 2], i3 = s_se[p + 3];
            ushort4 f0 = *(const ushort4*)&featb[(size_t)i0.x * FIN + lane * 4];
            ushort4 f1 = *(const ushort4*)&featb[(size_t)i1.x * FIN + lane * 4];
            ushort4 f2 = *(const ushort4*)&featb[(size_t)i2.x * FIN + lane * 4];
            ushort4 f3 = *(const ushort4*)&featb[(size_t)i3.x * FIN + lane * 4];
            float e0 = __builtin_nontemporal_load(&edge_feat[(size_t)i0.y * FE + lane]);
            float e1 = __builtin_nontemporal_load(&edge_feat[(size_t)i1.y * FE + lane]);
            float e2f = __builtin_nontemporal_load(&edge_feat[(size_t)i2.y * FE + lane]);
            float e3 = __builtin_nontemporal_load(&edge_feat[(size_t)i3.y * FE + lane]);
            h0 += (bfu(f0.x) + bfu(f1.x)) + (bfu(f2.x) + bfu(f3.x));
            h1 += (bfu(f0.y) + bfu(f1.y)) + (bfu(f2.y) + bfu(f3.y));
            h2 += (bfu(f0.z) + bfu(f1.z)) + (bfu(f2.z) + bfu(f3.z));
            h3 += (bfu(f0.w) + bfu(f1.w)) + (bfu(f2.w) + bfu(f3.w));
            eacc += (e0 + e1) + (e2f + e3);
        }
        for (; p < e2; p++) {
            int2 a = s_se[p];
            ushort4 f0 = *(const ushort4*)&featb[(size_t)a.x * FIN + lane * 4];
            h0 += bfu(f0.x); h1 += bfu(f0.y); h2 += bfu(f0.z); h3 += bfu(f0.w);
            eacc += __builtin_nontemporal_load(&edge_feat[(size_t)a.y * FE + lane]);
        }
    }
    if (sub == 1) {
        red[ln][0][lane] = h0;
        red[ln][1][lane] = h1;
        red[ln][2][lane] = h2;
        red[ln][3][lane] = h3;
        red[ln][4][lane] = eacc;
    }
    __syncthreads();
    if (sub == 0 && n < N) {
        h0 += red[ln][0][lane];
        h1 += red[ln][1][lane];
        h2 += red[ln][2][lane];
        h3 += red[ln][3][lane];
        eacc += red[ln][4][lane];
        ushort4 o;
        o.x = f2bf(h0); o.y = f2bf(h1); o.z = f2bf(h2); o.w = f2bf(h3);
        *(ushort4*)&aggb[(size_t)n * KTOT + lane * 4] = o;    // channels 0..255
        aggb[(size_t)n * KTOT + FIN + lane] = f2bf(eacc);     // channels 256..319
    }
}

// ---------------- pass 5: MFMA GEMM K=320, fused epilogue relu(norm_in*X + bias) ----

#define GTM 128
#define GBK 64
#define ALD 72   // LDS row stride in bf16 (64+8 pad)

__global__ __launch_bounds__(256) void k_gemm_fused(const unsigned short* __restrict__ A,
                                                    int M,
                                                    const unsigned short* __restrict__ Wt,
                                                    const float* __restrict__ norm_in,
                                                    const float* __restrict__ bias,
                                                    float* __restrict__ out) {
    __shared__ unsigned short As[GTM * ALD];
    __shared__ unsigned short Bs[GTM * ALD];
    int m0 = blockIdx.y * GTM;
    int n0 = blockIdx.x * GTM;
    int t = threadIdx.x;
    int wave = t >> 6, lane = t & 63;
    int wy = wave >> 1, wx = wave & 1;
    int quad = lane >> 4, l16 = lane & 15;

    f32x4 acc[4][4];
#pragma unroll
    for (int i = 0; i < 4; i++)
#pragma unroll
        for (int j = 0; j < 4; j++) acc[i][j] = (f32x4){0.f, 0.f, 0.f, 0.f};

    for (int k0 = 0; k0 < KTOT; k0 += GBK) {
#pragma unroll
        for (int q = 0; q < 4; q++) {
            int idx = t + q * 256;
            int row = idx >> 3;
            int c16 = idx & 7;
            int gm = m0 + row;
            uint4 v = make_uint4(0, 0, 0, 0);
            if (gm < M) v = *(const uint4*)&A[(size_t)gm * KTOT + k0 + c16 * 8];
            *(uint4*)&As[row * ALD + c16 * 8] = v;
        }
#pragma unroll
        for (int q = 0; q < 4; q++) {
            int idx = t + q * 256;
            int row = idx >> 3;
            int c16 = idx & 7;
            uint4 v = *(const uint4*)&Wt[(size_t)(n0 + row) * KTOT + k0 + c16 * 8];
            *(uint4*)&Bs[row * ALD + c16 * 8] = v;
        }
        __syncthreads();
#pragma unroll
        for (int kk = 0; kk < GBK / 32; kk++) {
            short8 af[4], bf[4];
#pragma unroll
            for (int i = 0; i < 4; i++) {
                af[i] = *(const short8*)&As[(wy * 64 + i * 16 + l16) * ALD + kk * 32 + quad * 8];
                bf[i] = *(const short8*)&Bs[(wx * 64 + i * 16 + l16) * ALD + kk * 32 + quad * 8];
            }
#pragma unroll
            for (int i = 0; i < 4; i++)
#pragma unroll
                for (int j = 0; j < 4; j++)
                    acc[i][j] = __builtin_amdgcn_mfma_f32_16x16x32_bf16(af[i], bf[j], acc[i][j], 0, 0, 0);
        }
        __syncthreads();
    }

#pragma unroll
    for (int i = 0; i < 4; i++)
#pragma unroll
        for (int r = 0; r < 4; r++) {
            int gm = m0 + wy * 64 + i * 16 + quad * 4 + r;
            if (gm < M) {
                float ni = norm_in[gm];
#pragma unroll
                for (int j = 0; j < 4; j++) {
                    int gn = n0 + wx * 64 + j * 16 + l16;
                    float v = fmaxf(acc[i][j][r] * ni + bias[gn], 0.f);
                    out[(size_t)gm * FOUT + gn] = v;
                }
            }
        }
}

// ---------------- launch ----------------

extern "C" void kernel_launch(void* const* d_in, const int* in_sizes, int n_in,
                              void* d_out, int out_size, void* d_ws, size_t ws_size,
                              hipStream_t stream) {
    const float* feat      = (const float*)d_in[0];
    const float* edge_feat = (const float*)d_in[1];
    const float* weight    = (const float*)d_in[2];
    const float* bias      = (const float*)d_in[3];
    const int*   src       = (const int*)d_in[4];
    const int*   dst       = (const int*)d_in[5];
    int E = in_sizes[4];
    int N = in_sizes[0] / FIN;

    char* ws = (char*)d_ws;
    size_t off = 0;
    auto alloc = [&](size_t bytes) -> void* {
        void* p = ws + off;
        off += (bytes + 255) & ~(size_t)255;
        return p;
    };
    unsigned short* featb = (unsigned short*)alloc((size_t)N * FIN * 2);    // 25.6 MB
    unsigned short* aggb  = (unsigned short*)alloc((size_t)N * KTOT * 2);   // 32 MB
    unsigned short* wtt   = (unsigned short*)alloc((size_t)256 * KTOT * 2);
    // degree arrays: ONE allocation of 2N ints so in_deg = out_deg + N exactly,
    // and a single memset covers both (round-7 crash: allocator 256B-rounding
    // broke the adjacency assumption).
    int*   out_deg  = (int*)alloc((size_t)2 * N * 4);
    int*   in_deg   = out_deg + N;
    int*   row_ptr  = (int*)alloc((size_t)(N + 1) * 4);
    int*   cursor   = (int*)alloc((size_t)N * 4);
    float* norm_out = (float*)alloc((size_t)N * 4);
    float* norm_in  = (float*)alloc((size_t)N * 4);
    int2*  s_se     = (int2*)alloc((size_t)E * 8);
    (void)ws_size;

    int bE = (E + 255) / 256;
    int nchunk = (N + 1023) >> 10;

    hipMemsetAsync(out_deg, 0, (size_t)2 * N * 4, stream);

    k_deg_prepw<<<bE, 256, 0, stream>>>(src, dst, out_deg, in_deg, weight, wtt, E);
    k_scan<<<nchunk, 1024, 0, stream>>>(in_deg, out_deg, row_ptr, cursor,
                                        norm_out, norm_in, N);
    k_scatter_prepf<<<(N * 64 + 255) / 256, 256, 0, stream>>>(src, dst, cursor, s_se, E,
                                                              feat, norm_out, featb, N);

    // fused aggregation: aggb[n] = [sum featb[src], sum edge_feat[eid]] (bf16), 2 waves/node
    k_agg<<<(N + 1) / 2, 256, 0, stream>>>(featb, edge_feat, row_ptr, s_se, aggb, N);

    // fused GEMM + epilogue: out = relu(norm_in * (aggb @ Wt) + bias)
    dim3 gg(FOUT / GTM, (N + GTM - 1) / GTM);
    k_gemm_fused<<<gg, 256, 0, stream>>>(aggb, N, wtt, norm_in, bias, (float*)d_out);
}